// Round 4
// baseline (590.937 us; speedup 1.0000x reference)
//
#include <hip/hip_runtime.h>
#include <math.h>

// ---- problem constants ----
#define D    128
#define TT   128
#define E    100
#define NHD  2
#define BSZ  2048
#define N0C  6144
#define K0C  5
#define N1C  30720
#define K1C  10
#define NNC  200000
#define MC   4096
#define MSG  484
#define KIN  356        // D+E+T
#define GK   612        // MSG + D (GRU GEMM K)
#define GKP  616        // padded to 8
#define GN   512        // GRU GEMM N (256 rz-sum + 128 in + 128 hn)

typedef __attribute__((ext_vector_type(8))) short short8v;   // 8 bf16 (4 VGPRs)
typedef __attribute__((ext_vector_type(4))) float f32x4;

__device__ __forceinline__ float sigmoidf_(float x){ return 1.f/(1.f+__expf(-x)); }
__device__ __forceinline__ unsigned short f2b(float f){
    unsigned int x = __float_as_uint(f);
    unsigned int r = (x + 0x7fffu + ((x>>16)&1u)) >> 16;
    return (unsigned short)r;
}
__device__ __forceinline__ float b2f(unsigned short u){
    return __uint_as_float(((unsigned int)u)<<16);
}

// ---------- precompute: qc (time-const query bias), cb (fused out bias), gru bias ----------
__global__ void k_pre_small(const float* time_b,
                            const float* Wq0,const float* bq0,const float* Wq1,const float* bq1,
                            const float* bv0,const float* Wo0,const float* bo0,
                            const float* bv1,const float* Wo1,const float* bo1,
                            const float* bih,const float* bhh,float* gBias,
                            float* qc0, float* qc1, float* cb0, float* cb1){
    __shared__ float cosb[TT];
    int j = threadIdx.x; // 512 threads
    if(j < TT) cosb[j] = cosf(time_b[j]);
    __syncthreads();
    if(j < 128){
        float a0=bq0[j], a1=bq1[j];
        for(int t=0;t<TT;++t){ a0 += cosb[t]*Wq0[(D+t)*D + j]; a1 += cosb[t]*Wq1[(D+t)*D + j]; }
        qc0[j]=a0; qc1[j]=a1;
        float c0=bo0[j], c1=bo1[j];
        for(int jp=0;jp<D;++jp){ c0 += bv0[jp]*Wo0[jp*D + j]; c1 += bv1[jp]*Wo1[jp*D + j]; }
        cb0[j]=c0; cb1[j]=c1;
    }
    if(j < GN){
        float v;
        if(j < 256)      v = bih[j] + bhh[j];
        else if(j < 384) v = bih[j];
        else             v = bhh[j-128];
        gBias[j] = v;
    }
}

// WF (bf16), head h at col h*hstr + cl, cl in [0,span] (cl==span is qb col = bk-derived)
// hstr = span + 4 (pad cols zeroed); width = 2*hstr
__global__ void k_wf(const float* Wq,const float* Wk,const float* bk,const float* qc,
                     unsigned short* WF, float* cF, int cmin){
    int span = 356 - cmin;
    int hstr = span + 4;
    int width = 2*hstr;
    int idx = blockIdx.x;            // [0, 2*hstr)
    int h = idx / hstr; int cl = idx % hstr;
    int k = threadIdx.x;
    if(cl > span){
        WF[(size_t)k*width + idx] = (unsigned short)0;
        if(k==0) cF[idx] = 0.f;
        return;
    }
    int c = cmin + cl;
    float a = 0.f;
    for(int d=0; d<64; ++d){
        float wkv = (c < KIN) ? Wk[c*D + h*64+d] : bk[h*64+d];
        a += Wq[k*D + h*64+d] * wkv;
    }
    WF[(size_t)k*width + idx] = f2b(a);
    if(k==0){
        float s=0.f;
        for(int d=0; d<64; ++d){
            float wkv = (c < KIN) ? Wk[c*D + h*64+d] : bk[h*64+d];
            s += qc[h*64+d]*wkv;
        }
        cF[idx] = s;
    }
}

// Bcat (bf16): rows [0, 2*span) = fused Wvo rows; rows [2*span, +128) = Wo bottom half
__global__ void k_bcat(const float* Wv, const float* Wo, unsigned short* Bcat, int cmin){
    int span = KIN - cmin; int rows = 2*span;
    int r = blockIdx.x; int j = threadIdx.x;
    float a;
    if(r < rows){
        int h = r/span; int c = cmin + (r - h*span);
        a = 0.f;
        for(int d=0; d<64; ++d) a += Wv[c*D + h*64+d] * Wo[(h*64+d)*D + j];
    } else {
        a = Wo[(size_t)(D + (r - rows))*D + j];
    }
    Bcat[(size_t)r*D + j] = f2b(a);
}

// ---------- GRU as GEMM: packed B (612 x 512 bf16) via coalesced LDS transpose ----------
__global__ __launch_bounds__(256) void k_gruB(const float* Wih, const float* Whh, unsigned short* B){
    __shared__ float tile[64][65];
    int rb = blockIdx.x*64;
    int jb = blockIdx.y*64;
    int t = threadIdx.x;
    int rr = t&63, jj0 = t>>6;
    #pragma unroll
    for(int i=0;i<16;++i){
        int jj = jj0 + i*4;
        int j = jb + jj; int r = rb + rr;
        float v = 0.f;
        if(r < GK){
            if(j < 256)      v = (r<MSG)? Wih[(size_t)j*MSG+r] : Whh[(size_t)j*D + (r-MSG)];
            else if(j < 384) v = (r<MSG)? Wih[(size_t)j*MSG+r] : 0.f;
            else             v = (r<MSG)? 0.f : Whh[(size_t)(j-128)*D + (r-MSG)];
        }
        tile[jj][rr] = v;
    }
    __syncthreads();
    int jw = t&63, rr0 = t>>6;
    #pragma unroll
    for(int i=0;i<16;++i){
        int rr2 = rr0 + i*4;
        int r = rb + rr2;
        if(r < GK) B[(size_t)r*GN + jb + jw] = f2b(tile[jw][rr2]);
    }
}
// A-matrix convert + map scatter fused (map entries validated on read, no init needed)
__global__ void k_acvt(const float* msgs, const float* memory, const int* msg_nids,
                       unsigned short* ab, float* hprevf, int* map){
    int i = blockIdx.x*256 + threadIdx.x;
    if(i >= MC*GKP) return;
    int row = i / GKP; int c = i - row*GKP;
    if(c == 0) map[msg_nids[row]] = row;
    float v;
    if(c < MSG) v = msgs[(size_t)row*MSG + c];
    else if(c < GK){ int d = c-MSG; v = memory[(size_t)msg_nids[row]*D + d]; hprevf[row*D+d] = v; }
    else v = 0.f;
    ab[i] = f2b(v);
}
// fused split-K reduce + gates: upd = (1-u)*tanh(inn + r*hn) + u*h
__global__ void k_gates3(const float* part, const float* bias, const float* hprevf, float* upd){
    int i = blockIdx.x*256 + threadIdx.x;
    if(i >= MC*D) return;
    int row = i>>7, d = i&127;
    const float* p = part + (size_t)row*GN;
    const size_t S = (size_t)MC*GN;
    float gr = p[d]     + p[S+d]     + p[2*S+d]     + bias[d];
    float gu = p[128+d] + p[S+128+d] + p[2*S+128+d] + bias[128+d];
    float gi = p[256+d] + p[S+256+d] + p[2*S+256+d] + bias[256+d];
    float gh = p[384+d] + p[S+384+d] + p[2*S+384+d] + bias[384+d];
    float r = sigmoidf_(gr);
    float u = sigmoidf_(gu);
    float n = tanhf(gi + r*gh);
    upd[i] = (1.f-u)*n + u*hprevf[i];
}

// fused gather for both hops; map entry valid iff msg_nids[mi]==sid (no map init required)
__global__ void k_gatherf(const int* seed1,const int* seed0,const int* map,const int* msg_nids,
                          const float* memory,const float* upd,
                          unsigned short* hb1, unsigned short* acat1,
                          unsigned short* hb0, unsigned short* acat0){
    int i = blockIdx.x*256 + threadIdx.x;
    const int total1 = N1C*D;
    int li; const int* seed; unsigned short* hb; unsigned short* acat; int ldav, hoff;
    if(i < total1){ li=i; seed=seed1; hb=hb1; acat=acat1; ldav=584; hoff=456; }
    else { li = i - total1; if(li >= N0C*D) return; seed=seed0; hb=hb0; acat=acat0; ldav=840; hoff=712; }
    int row = li>>7, c = li&127;
    int sid = seed[row];
    int mi = map[sid];
    bool valid = ((unsigned)mi < (unsigned)MC) && (msg_nids[mi] == sid);
    float v = valid ? upd[(size_t)mi*D + c] : memory[(size_t)sid*D + c];
    unsigned short u = f2b(v);
    hb[li] = u;
    acat[(size_t)row*ldav + hoff + c] = u;
}

// ---------- bf16 MFMA GEMM, reg-prefetch pipelined, optional split-K ----------
// SPLITK>1: writes f32 partials [z][M][ldc], no bias/relu
template<int BM, int SPLITK, bool RELU, bool OUTF32>
__global__ __launch_bounds__(256) void k_gmm(const unsigned short* A, int lda,
                                             const unsigned short* B, int ldb,
                                             const float* bias, void* Cp, int ldc,
                                             int K, int N, int M){
    constexpr int ASTR = 72;
    constexpr int BSTR = 72;
    constexpr int RPW = BM/4;
    constexpr int RT  = RPW/16;
    constexpr int AIT = BM/32;
    __shared__ unsigned short As[BM*ASTR];
    __shared__ unsigned short Bs[64*BSTR];
    int t = threadIdx.x;
    int wave = t>>6, lane = t&63;
    int l15 = lane&15, l4 = lane>>4;
    int m0 = blockIdx.y*BM, n0 = blockIdx.x*64;
    int ntiles = (K+63)>>6;
    int tbeg, tend;
    if(SPLITK==1){ tbeg=0; tend=ntiles; }
    else {
        int tper = (ntiles + SPLITK-1)/SPLITK;
        tbeg = blockIdx.z*tper;
        tend = min(ntiles, tbeg+tper);
    }
    f32x4 acc[RT][4];
    #pragma unroll
    for(int rt=0;rt<RT;++rt)
        #pragma unroll
        for(int ct=0;ct<4;++ct) acc[rt][ct] = (f32x4){0.f,0.f,0.f,0.f};

    uint4 apre[AIT]; unsigned short bpre[16];
    auto loadA = [&](int kt){
        int k0 = kt<<6;
        #pragma unroll
        for(int i=0;i<AIT;++i){
            int idx = t + i*256;
            int row = idx>>3; int kc = (idx&7)*8;
            uint4 v = {0u,0u,0u,0u};
            if(k0+kc < K) v = *(const uint4*)(A + (size_t)(m0+row)*lda + k0 + kc);
            apre[i] = v;
        }
    };
    auto loadB = [&](int kt){
        int k0 = kt<<6;
        int n = t&63; int kb = (t>>6)*16;
        int ng = n0+n;
        #pragma unroll
        for(int j=0;j<16;++j){
            int kg = k0 + kb + j;
            bpre[j] = (kg<K && ng<N) ? B[(size_t)kg*ldb + ng] : (unsigned short)0;
        }
    };
    auto stash = [&](){
        #pragma unroll
        for(int i=0;i<AIT;++i){
            int idx = t + i*256;
            int row = idx>>3; int kc = (idx&7)*8;
            *(uint4*)&As[row*ASTR + kc] = apre[i];
        }
        int n = t&63; int kb = (t>>6)*16;
        #pragma unroll
        for(int j=0;j<16;++j) Bs[n*BSTR + kb + j] = bpre[j];
    };

    loadA(tbeg); loadB(tbeg);
    for(int kt=tbeg; kt<tend; ++kt){
        stash();
        __syncthreads();
        if(kt+1 < tend){ loadA(kt+1); loadB(kt+1); }
        #pragma unroll
        for(int kk=0; kk<64; kk+=32){
            short8v bfr[4];
            #pragma unroll
            for(int ct=0;ct<4;++ct)
                bfr[ct] = *(const short8v*)&Bs[(ct*16+l15)*BSTR + kk + l4*8];
            #pragma unroll
            for(int rt=0;rt<RT;++rt){
                short8v afr = *(const short8v*)&As[(wave*RPW + rt*16 + l15)*ASTR + kk + l4*8];
                #pragma unroll
                for(int ct=0;ct<4;++ct)
                    acc[rt][ct] = __builtin_amdgcn_mfma_f32_16x16x32_bf16(afr, bfr[ct], acc[rt][ct], 0,0,0);
            }
        }
        __syncthreads();
    }
    #pragma unroll
    for(int rt=0;rt<RT;++rt){
        #pragma unroll
        for(int ct=0;ct<4;++ct){
            int col = n0 + ct*16 + l15;
            if(col < N){
                #pragma unroll
                for(int r=0;r<4;++r){
                    int row = m0 + wave*RPW + rt*16 + l4*4 + r;
                    if(SPLITK==1){
                        float v = acc[rt][ct][r] + bias[col];
                        if(RELU) v = fmaxf(v, 0.f);
                        if(OUTF32) ((float*)Cp)[(size_t)row*ldc + col] = v;
                        else ((unsigned short*)Cp)[(size_t)row*ldc + col] = f2b(v);
                    } else {
                        ((float*)Cp)[((size_t)blockIdx.z*M + row)*ldc + col] = acc[rt][ct][r];
                    }
                }
            }
        }
    }
}

// split-K reduce + bias (+relu); N power of two
template<int SPL, bool RELU, bool OUTF32>
__global__ void k_kred(const float* part, int M, int N, const float* bias, void* out){
    int i = blockIdx.x*256 + threadIdx.x;
    if(i >= M*N) return;
    int col = i & (N-1);
    float v = bias[col];
    #pragma unroll
    for(int z=0;z<SPL;++z) v += part[(size_t)z*M*N + i];
    if(RELU) v = fmaxf(v, 0.f);
    if(OUTF32) ((float*)out)[i] = v;
    else ((unsigned short*)out)[i] = f2b(v);
}

// fused scores + masked softmax + av.
// Key structure (round-3): kin staged in per-wave LDS (compiler cannot rematerialize
// it back to global re-loads + re-cos, which is what it did to the register array —
// VGPR_Count 44 proved remat). Phase 1 stays BRANCHLESS with masked loads gated to
// k=0's addresses (k=0 always active) so loads batch and masked traffic is L1-hit.
// Dot + AV phases skip masked k via wave-UNIFORM branches (mk in SGPRs) — they read
// only LDS so no load-serialization risk; bit-exact since masked weight is exactly 0.
template<int K, int CMIN, int S4, int NPW>
__global__ __launch_bounds__(256,4) void k_attn(const unsigned short* __restrict__ qwb,
    unsigned short* __restrict__ avout, int ldav,
    const float* __restrict__ times, const float* __restrict__ nbr_times,
    const float* __restrict__ nbr_feats,
    const int* __restrict__ nbr_mask, const int* __restrict__ nbr_local,
    const unsigned short* __restrict__ zbuf,
    const float* __restrict__ time_w, const float* __restrict__ time_b){
    constexpr int SPAN = KIN - CMIN;
    constexpr int QSTR = SPAN + 4;
    constexpr int QLD  = 2*QSTR;
    __shared__ float4 kls[4*K*S4*64];   // 40 KB: per-wave kin staging
    int w = threadIdx.x>>6;
    int wv = __builtin_amdgcn_readfirstlane(blockIdx.x*4 + w);
    int lane = threadIdx.x & 63;
    float4* myk = kls + w*(K*S4*64);

    float4 tw4[S4], tb4[S4];
    #pragma unroll
    for(int s=0;s<S4;++s){
        int c = CMIN + s*256 + lane*4;
        if(c >= D+E && c < KIN){
            tw4[s] = *(const float4*)(time_w + (c-(D+E)));
            tb4[s] = *(const float4*)(time_b + (c-(D+E)));
        } else {
            tw4[s] = make_float4(0.f,0.f,0.f,0.f);
            tb4[s] = make_float4(0.f,0.f,0.f,0.f);
        }
    }

    #pragma unroll
    for(int i=0;i<NPW;++i){
        int n = wv*NPW + i;
        const unsigned short* qrow = qwb + (size_t)n*QLD;
        // wave-uniform scalar loads (SGPRs)
        float tn = times[n];
        int   mk[K]; float tk[K]; int nl[K];
        #pragma unroll
        for(int k=0;k<K;++k){
            mk[k] = nbr_mask [(size_t)n*K + k];
            tk[k] = nbr_times[(size_t)n*K + k];
            nl[k] = (CMIN==0) ? nbr_local[(size_t)n*K + k] : 0;
        }

        float4 qw4[NHD][S4]; float qb[NHD];
        #pragma unroll
        for(int h=0;h<NHD;++h){
            qb[h] = b2f(qrow[h*QSTR + SPAN]);
            #pragma unroll
            for(int s=0;s<S4;++s){
                int cl = s*256 + lane*4;
                float4 v = make_float4(0.f,0.f,0.f,0.f);
                if(cl < SPAN){
                    uint2 wq = *(const uint2*)(qrow + h*QSTR + cl);
                    v.x = __uint_as_float(wq.x<<16);
                    v.y = __uint_as_float(wq.x & 0xffff0000u);
                    v.z = __uint_as_float(wq.y<<16);
                    v.w = __uint_as_float(wq.y & 0xffff0000u);
                }
                qw4[h][s] = v;
            }
        }

        // phase 1: materialize kin for ALL neighbors into LDS.
        // Branchless; masked k reads k=0's addresses (always active) -> L1 hits,
        // values never consumed (dot/AV skip masked k).
        #pragma unroll
        for(int k=0;k<K;++k){
            int gk = (mk[k] > 0) ? k : 0;
            float dt = tn - tk[gk];
            const float* ef = nbr_feats + (size_t)(n*K+gk)*E;
            const unsigned short* zf = (CMIN==0) ?
                (zbuf + (size_t)(nl[gk] - N0C)*D) : (const unsigned short*)0;
            #pragma unroll
            for(int s=0;s<S4;++s){
                int c = CMIN + s*256 + lane*4;
                float4 kv = make_float4(0.f,0.f,0.f,0.f);
                if(c < KIN){
                    if(CMIN==0 && c < D){
                        uint2 wz = *(const uint2*)(zf + c);
                        kv.x = __uint_as_float(wz.x<<16);
                        kv.y = __uint_as_float(wz.x & 0xffff0000u);
                        kv.z = __uint_as_float(wz.y<<16);
                        kv.w = __uint_as_float(wz.y & 0xffff0000u);
                    } else if(c < D+E){
                        kv = *(const float4*)(ef + (c-D));
                    } else {
                        kv.x = __cosf(dt*tw4[s].x + tb4[s].x);
                        kv.y = __cosf(dt*tw4[s].y + tb4[s].y);
                        kv.z = __cosf(dt*tw4[s].z + tb4[s].z);
                        kv.w = __cosf(dt*tw4[s].w + tb4[s].w);
                    }
                }
                myk[(k*S4+s)*64 + lane] = kv;
            }
        }

        // phase 2: lane-partial dot products, active-only (uniform branch, LDS reads)
        float p0[K], p1[K];
        #pragma unroll
        for(int k=0;k<K;++k){ p0[k]=0.f; p1[k]=0.f; }
        #pragma unroll
        for(int k=0;k<K;++k){
            if(mk[k] > 0){
                float a0 = 0.f, a1 = 0.f;
                #pragma unroll
                for(int s=0;s<S4;++s){
                    float4 kv = myk[(k*S4+s)*64 + lane];
                    a0 += kv.x*qw4[0][s].x + kv.y*qw4[0][s].y + kv.z*qw4[0][s].z + kv.w*qw4[0][s].w;
                    a1 += kv.x*qw4[1][s].x + kv.y*qw4[1][s].y + kv.z*qw4[1][s].z + kv.w*qw4[1][s].w;
                }
                p0[k] = a0; p1[k] = a1;
            }
        }

        // phase 3: one interleaved butterfly — 2K independent chains per step
        #pragma unroll
        for(int off=32; off; off>>=1){
            #pragma unroll
            for(int k=0;k<K;++k){
                p0[k] += __shfl_xor(p0[k], off);
                p1[k] += __shfl_xor(p1[k], off);
            }
        }

        float sval[NHD][K];
        #pragma unroll
        for(int k=0;k<K;++k){
            bool act = mk[k] > 0;
            sval[0][k] = act ? (p0[k] + qb[0])*0.125f : -1e9f;
            sval[1][k] = act ? (p1[k] + qb[1])*0.125f : -1e9f;
        }
        #pragma unroll
        for(int h=0;h<NHD;++h){
            float mx = -1e30f;
            #pragma unroll
            for(int k=0;k<K;++k) mx = fmaxf(mx, sval[h][k]);
            float z=0.f;
            #pragma unroll
            for(int k=0;k<K;++k){ float e = __expf(sval[h][k]-mx); sval[h][k]=e; z+=e; }
            float inv = 1.f/z;
            #pragma unroll
            for(int k=0;k<K;++k) sval[h][k]*=inv;
        }

        // AV: s-outer so each LDS kin read serves both heads; active-only (exact: masked w==0)
        #pragma unroll
        for(int s=0;s<S4;++s){
            int cl = s*256 + lane*4;
            if(cl < SPAN){
                float a00=0.f,a01=0.f,a02=0.f,a03=0.f;
                float a10=0.f,a11=0.f,a12=0.f,a13=0.f;
                #pragma unroll
                for(int k=0;k<K;++k){
                    if(mk[k] > 0){
                        float4 kv = myk[(k*S4+s)*64 + lane];
                        float w0 = sval[0][k], w1 = sval[1][k];
                        a00 += w0*kv.x; a01 += w0*kv.y; a02 += w0*kv.z; a03 += w0*kv.w;
                        a10 += w1*kv.x; a11 += w1*kv.y; a12 += w1*kv.z; a13 += w1*kv.w;
                    }
                }
                uint2 o0, o1;
                o0.x = (unsigned int)f2b(a00) | ((unsigned int)f2b(a01)<<16);
                o0.y = (unsigned int)f2b(a02) | ((unsigned int)f2b(a03)<<16);
                o1.x = (unsigned int)f2b(a10) | ((unsigned int)f2b(a11)<<16);
                o1.y = (unsigned int)f2b(a12) | ((unsigned int)f2b(a13)<<16);
                *(uint2*)(avout + (size_t)n*ldav + cl)        = o0;
                *(uint2*)(avout + (size_t)n*ldav + SPAN + cl) = o1;
            }
        }
    }
}

// link prediction
__global__ __launch_bounds__(128) void k_linkpred(const float* z0,
      const int* src,const int* dst,const int* neg,
      const float* Ws,const float* bs,const float* Wd,const float* bd,
      const float* Wo,const float* bo, float* out){
    __shared__ float zs[D], zd[D], zn[D];
    __shared__ float red[4];
    int b = blockIdx.x; int d = threadIdx.x;
    zs[d] = z0[(size_t)src[b]*D + d];
    zd[d] = z0[(size_t)dst[b]*D + d];
    zn[d] = z0[(size_t)neg[b]*D + d];
    __syncthreads();
    float ss=0.f, sdd=0.f, snn=0.f;
    for(int c=0;c<D;++c){
        float w1 = Ws[c*D + d], w2 = Wd[c*D + d];
        ss  += zs[c]*w1; sdd += zd[c]*w2; snn += zn[c]*w2;
    }
    float bb = bs[d] + bd[d];
    float h1 = fmaxf(ss + sdd + bb, 0.f);
    float h2 = fmaxf(ss + snn + bb, 0.f);
    float w = Wo[d];
    float v1 = h1*w, v2 = h2*w;
    #pragma unroll
    for(int off=32; off; off>>=1){ v1 += __shfl_xor(v1,off); v2 += __shfl_xor(v2,off); }
    int wid = d>>6;
    if((d&63)==0){ red[wid*2]=v1; red[wid*2+1]=v2; }
    __syncthreads();
    if(d==0){
        out[b]       = sigmoidf_(red[0]+red[2] + bo[0]);
        out[BSZ + b] = sigmoidf_(red[1]+red[3] + bo[0]);
    }
}

extern "C" void kernel_launch(void* const* d_in, const int* in_sizes, int n_in,
                              void* d_out, int out_size, void* d_ws, size_t ws_size,
                              hipStream_t stream) {
    const float* memory  = (const float*)d_in[0];
    const float* time_w  = (const float*)d_in[1];
    const float* time_b  = (const float*)d_in[2];
    const float* gWih    = (const float*)d_in[3];
    const float* gbih    = (const float*)d_in[4];
    const float* gWhh    = (const float*)d_in[5];
    const float* gbhh    = (const float*)d_in[6];
    const float* Wq0=(const float*)d_in[7],  *bq0=(const float*)d_in[8];
    const float* Wk0=(const float*)d_in[9],  *bk0=(const float*)d_in[10];
    const float* Wv0=(const float*)d_in[11], *bv0=(const float*)d_in[12];
    const float* Wo0=(const float*)d_in[13], *bo0=(const float*)d_in[14];
    const float* Wq1=(const float*)d_in[15], *bq1=(const float*)d_in[16];
    const float* Wk1=(const float*)d_in[17], *bk1=(const float*)d_in[18];
    const float* Wv1=(const float*)d_in[19], *bv1=(const float*)d_in[20];
    const float* Wo1=(const float*)d_in[21], *bo1=(const float*)d_in[22];
    const float* lpWs=(const float*)d_in[23], *lpbs=(const float*)d_in[24];
    const float* lpWd=(const float*)d_in[25], *lpbd=(const float*)d_in[26];
    const float* lpWo=(const float*)d_in[27], *lpbo=(const float*)d_in[28];
    const float* msgs    = (const float*)d_in[29];
    const float* times0  = (const float*)d_in[30];
    const float* ntimes0 = (const float*)d_in[31];
    const float* nfeats0 = (const float*)d_in[32];
    const float* times1  = (const float*)d_in[33];
    const float* ntimes1 = (const float*)d_in[34];
    const float* nfeats1 = (const float*)d_in[35];
    const int* msg_nids  = (const int*)d_in[36];
    const int* seed0     = (const int*)d_in[37];
    const int* seed1     = (const int*)d_in[38];
    const int* nbr_local0= (const int*)d_in[39];
    const int* nbr_mask0 = (const int*)d_in[40];
    const int* nbr_mask1 = (const int*)d_in[41];
    const int* src       = (const int*)d_in[42];
    const int* dst       = (const int*)d_in[43];
    const int* neg       = (const int*)d_in[44];

    char* ws = (char*)d_ws;
    size_t off = 0;
    auto alloc = [&](size_t bytes)->char*{
        char* p = ws + off;
        off += (bytes + 255) & ~(size_t)255;
        return p;
    };
    int*   map   = (int*)  alloc((size_t)NNC*4);
    float* upd   = (float*)alloc((size_t)MC*D*4);
    unsigned short* hb1   = (unsigned short*)alloc((size_t)N1C*D*2);
    unsigned short* qwb1  = (unsigned short*)alloc((size_t)N1C*464*2);
    unsigned short* acat1 = (unsigned short*)alloc((size_t)N1C*584*2);
    unsigned short* zb1   = (unsigned short*)alloc((size_t)N1C*D*2);
    unsigned short* hb0   = (unsigned short*)alloc((size_t)N0C*D*2);
    unsigned short* qwb0  = (unsigned short*)alloc((size_t)N0C*720*2);
    unsigned short* acat0 = (unsigned short*)alloc((size_t)N0C*840*2);
    float* z0    = (float*)alloc((size_t)N0C*D*4);
    float* qc0   = (float*)alloc(512);
    float* qc1   = (float*)alloc(512);
    float* cb0   = (float*)alloc(512);
    float* cb1   = (float*)alloc(512);
    unsigned short* WFb0 = (unsigned short*)alloc((size_t)D*720*2);
    unsigned short* WFb1 = (unsigned short*)alloc((size_t)D*464*2);
    float* cF0   = (float*)alloc((size_t)720*4);
    float* cF1   = (float*)alloc((size_t)464*4);
    unsigned short* Bcat1 = (unsigned short*)alloc((size_t)584*D*2);
    unsigned short* Bcat0 = (unsigned short*)alloc((size_t)840*D*2);
    unsigned short* gA    = (unsigned short*)alloc((size_t)MC*GKP*2);
    unsigned short* gB    = (unsigned short*)alloc((size_t)GK*GN*2);
    float* gBias = (float*)alloc((size_t)GN*4);
    float* hprevf= (float*)alloc((size_t)MC*D*4);
    float* part  = (float*)alloc((size_t)2*N1C*D*4);   // 31.5 MB, shared by all split-K
    float* outp = (float*)d_out;

    // precompute (gru bias fused in)
    k_pre_small<<<1,512,0,stream>>>(time_b, Wq0,bq0,Wq1,bq1, bv0,Wo0,bo0, bv1,Wo1,bo1,
                                    gbih, gbhh, gBias, qc0,qc1,cb0,cb1);
    k_wf<<<720,128,0,stream>>>(Wq0,Wk0,bk0,qc0, WFb0,cF0, 0);
    k_wf<<<464,128,0,stream>>>(Wq1,Wk1,bk1,qc1, WFb1,cF1, 128);
    k_bcat<<<584,128,0,stream>>>(Wv1, Wo1, Bcat1, 128);
    k_bcat<<<840,128,0,stream>>>(Wv0, Wo0, Bcat0, 0);
    k_gruB<<<dim3(10,8),256,0,stream>>>(gWih, gWhh, gB);

    // GRU memory update via split-K MFMA GEMM + fused reduce/gates (map scatter fused in acvt)
    k_acvt<<<(MC*GKP+255)/256,256,0,stream>>>(msgs, memory, msg_nids, gA, hprevf, map);
    k_gmm<128,3,false,true><<<dim3(GN/64, MC/128, 3),256,0,stream>>>(gA,GKP, gB,GN, gBias, part,GN, GK, GN, MC);
    k_gates3<<<(MC*D+255)/256,256,0,stream>>>(part, gBias, hprevf, upd);

    // gather node states (both hops) -> bf16
    k_gatherf<<<((N1C+N0C)*D)/256,256,0,stream>>>(seed1, seed0, map, msg_nids, memory, upd,
                                                  hb1, acat1, hb0, acat0);

    // GEMM1 (MFMA): qw = h @ WF + cF
    k_gmm<128,1,false,false><<<dim3(8,  N1C/128),256,0,stream>>>(hb1,128, WFb1,464, cF1, qwb1,464, 128, 464, N1C);
    k_gmm<128,1,false,false><<<dim3(12, N0C/128),256,0,stream>>>(hb0,128, WFb0,720, cF0, qwb0,720, 128, 720, N0C);

    // hop 1 attention (7680 blocks)
    k_attn<K1C,128,1,1><<<N1C/4,256,0,stream>>>(qwb1, acat1, 584, times1, ntimes1, nfeats1,
                                                nbr_mask1, (const int*)0, (const unsigned short*)0,
                                                time_w, time_b);
    // GEMM2 hop1: split-K=2 (960 blocks) + reduce -> bf16 zb1
    k_gmm<128,2,true,false><<<dim3(2, N1C/128, 2),256,0,stream>>>(acat1,584, Bcat1,D, cb1, part,D, 584, D, N1C);
    k_kred<2,true,false><<<(N1C*D+255)/256,256,0,stream>>>(part, N1C, D, cb1, zb1);

    // hop 0 attention (1536 blocks)
    k_attn<K0C,0,2,1><<<N0C/4,256,0,stream>>>(qwb0, acat0, 840, times0, ntimes0, nfeats0,
                                              nbr_mask0, nbr_local0, zb1,
                                              time_w, time_b);
    // GEMM2 hop0: BM=64, split-K=4 (768 blocks) + reduce -> f32 z0
    k_gmm<64,4,true,true><<<dim3(2, N0C/64, 4),256,0,stream>>>(acat0,840, Bcat0,D, cb0, part,D, 840, D, N0C);
    k_kred<4,true,true><<<(N0C*D+255)/256,256,0,stream>>>(part, N0C, D, cb0, z0);

    // link prediction
    k_linkpred<<<BSZ,128,0,stream>>>(z0, src,dst,neg, lpWs,lpbs,lpWd,lpbd, lpWo,lpbo, outp);
}

// Round 9
// 583.371 us; speedup vs baseline: 1.0130x; 1.0130x over previous
//
#include <hip/hip_runtime.h>
#include <math.h>

// ---- problem constants ----
#define D    128
#define TT   128
#define E    100
#define NHD  2
#define BSZ  2048
#define N0C  6144
#define K0C  5
#define N1C  30720
#define K1C  10
#define NNC  200000
#define MC   4096
#define MSG  484
#define KIN  356        // D+E+T
#define GK   612        // MSG + D (GRU GEMM K)
#define GKP  616        // padded to 8
#define GN   512        // GRU GEMM N (256 rz-sum + 128 in + 128 hn)

typedef __attribute__((ext_vector_type(8))) short short8v;   // 8 bf16 (4 VGPRs)
typedef __attribute__((ext_vector_type(4))) float f32x4;

__device__ __forceinline__ float sigmoidf_(float x){ return 1.f/(1.f+__expf(-x)); }
__device__ __forceinline__ unsigned short f2b(float f){
    unsigned int x = __float_as_uint(f);
    unsigned int r = (x + 0x7fffu + ((x>>16)&1u)) >> 16;
    return (unsigned short)r;
}
__device__ __forceinline__ float b2f(unsigned short u){
    return __uint_as_float(((unsigned int)u)<<16);
}
// opaque register pin: forbids rematerialization of v past this point
__device__ __forceinline__ void pin4(float4& v){
    float a=v.x, b=v.y, c=v.z, d=v.w;
    asm volatile("" : "+v"(a), "+v"(b), "+v"(c), "+v"(d));
    v.x=a; v.y=b; v.z=c; v.w=d;
}

// ---------- precompute: qc (time-const query bias), cb (fused out bias), gru bias ----------
__global__ void k_pre_small(const float* time_b,
                            const float* Wq0,const float* bq0,const float* Wq1,const float* bq1,
                            const float* bv0,const float* Wo0,const float* bo0,
                            const float* bv1,const float* Wo1,const float* bo1,
                            const float* bih,const float* bhh,float* gBias,
                            float* qc0, float* qc1, float* cb0, float* cb1){
    __shared__ float cosb[TT];
    int j = threadIdx.x; // 512 threads
    if(j < TT) cosb[j] = cosf(time_b[j]);
    __syncthreads();
    if(j < 128){
        float a0=bq0[j], a1=bq1[j];
        for(int t=0;t<TT;++t){ a0 += cosb[t]*Wq0[(D+t)*D + j]; a1 += cosb[t]*Wq1[(D+t)*D + j]; }
        qc0[j]=a0; qc1[j]=a1;
        float c0=bo0[j], c1=bo1[j];
        for(int jp=0;jp<D;++jp){ c0 += bv0[jp]*Wo0[jp*D + j]; c1 += bv1[jp]*Wo1[jp*D + j]; }
        cb0[j]=c0; cb1[j]=c1;
    }
    if(j < GN){
        float v;
        if(j < 256)      v = bih[j] + bhh[j];
        else if(j < 384) v = bih[j];
        else             v = bhh[j-128];
        gBias[j] = v;
    }
}

// WF (bf16), head h at col h*hstr + cl, cl in [0,span] (cl==span is qb col = bk-derived)
// hstr = span + 4 (pad cols zeroed); width = 2*hstr
__global__ void k_wf(const float* Wq,const float* Wk,const float* bk,const float* qc,
                     unsigned short* WF, float* cF, int cmin){
    int span = 356 - cmin;
    int hstr = span + 4;
    int width = 2*hstr;
    int idx = blockIdx.x;            // [0, 2*hstr)
    int h = idx / hstr; int cl = idx % hstr;
    int k = threadIdx.x;
    if(cl > span){
        WF[(size_t)k*width + idx] = (unsigned short)0;
        if(k==0) cF[idx] = 0.f;
        return;
    }
    int c = cmin + cl;
    float a = 0.f;
    for(int d=0; d<64; ++d){
        float wkv = (c < KIN) ? Wk[c*D + h*64+d] : bk[h*64+d];
        a += Wq[k*D + h*64+d] * wkv;
    }
    WF[(size_t)k*width + idx] = f2b(a);
    if(k==0){
        float s=0.f;
        for(int d=0; d<64; ++d){
            float wkv = (c < KIN) ? Wk[c*D + h*64+d] : bk[h*64+d];
            s += qc[h*64+d]*wkv;
        }
        cF[idx] = s;
    }
}

// Bcat (bf16): rows [0, 2*span) = fused Wvo rows; rows [2*span, +128) = Wo bottom half
__global__ void k_bcat(const float* Wv, const float* Wo, unsigned short* Bcat, int cmin){
    int span = KIN - cmin; int rows = 2*span;
    int r = blockIdx.x; int j = threadIdx.x;
    float a;
    if(r < rows){
        int h = r/span; int c = cmin + (r - h*span);
        a = 0.f;
        for(int d=0; d<64; ++d) a += Wv[c*D + h*64+d] * Wo[(h*64+d)*D + j];
    } else {
        a = Wo[(size_t)(D + (r - rows))*D + j];
    }
    Bcat[(size_t)r*D + j] = f2b(a);
}

// ---------- GRU as GEMM: packed B (612 x 512 bf16) via coalesced LDS transpose ----------
__global__ __launch_bounds__(256) void k_gruB(const float* Wih, const float* Whh, unsigned short* B){
    __shared__ float tile[64][65];
    int rb = blockIdx.x*64;
    int jb = blockIdx.y*64;
    int t = threadIdx.x;
    int rr = t&63, jj0 = t>>6;
    #pragma unroll
    for(int i=0;i<16;++i){
        int jj = jj0 + i*4;
        int j = jb + jj; int r = rb + rr;
        float v = 0.f;
        if(r < GK){
            if(j < 256)      v = (r<MSG)? Wih[(size_t)j*MSG+r] : Whh[(size_t)j*D + (r-MSG)];
            else if(j < 384) v = (r<MSG)? Wih[(size_t)j*MSG+r] : 0.f;
            else             v = (r<MSG)? 0.f : Whh[(size_t)(j-128)*D + (r-MSG)];
        }
        tile[jj][rr] = v;
    }
    __syncthreads();
    int jw = t&63, rr0 = t>>6;
    #pragma unroll
    for(int i=0;i<16;++i){
        int rr2 = rr0 + i*4;
        int r = rb + rr2;
        if(r < GK) B[(size_t)r*GN + jb + jw] = f2b(tile[jw][rr2]);
    }
}
// A-matrix convert + map scatter fused (map entries validated on read, no init needed)
__global__ void k_acvt(const float* msgs, const float* memory, const int* msg_nids,
                       unsigned short* ab, float* hprevf, int* map){
    int i = blockIdx.x*256 + threadIdx.x;
    if(i >= MC*GKP) return;
    int row = i / GKP; int c = i - row*GKP;
    if(c == 0) map[msg_nids[row]] = row;
    float v;
    if(c < MSG) v = msgs[(size_t)row*MSG + c];
    else if(c < GK){ int d = c-MSG; v = memory[(size_t)msg_nids[row]*D + d]; hprevf[row*D+d] = v; }
    else v = 0.f;
    ab[i] = f2b(v);
}
// fused split-K reduce + gates: upd = (1-u)*tanh(inn + r*hn) + u*h
__global__ void k_gates3(const float* part, const float* bias, const float* hprevf, float* upd){
    int i = blockIdx.x*256 + threadIdx.x;
    if(i >= MC*D) return;
    int row = i>>7, d = i&127;
    const float* p = part + (size_t)row*GN;
    const size_t S = (size_t)MC*GN;
    float gr = p[d]     + p[S+d]     + p[2*S+d]     + bias[d];
    float gu = p[128+d] + p[S+128+d] + p[2*S+128+d] + bias[128+d];
    float gi = p[256+d] + p[S+256+d] + p[2*S+256+d] + bias[256+d];
    float gh = p[384+d] + p[S+384+d] + p[2*S+384+d] + bias[384+d];
    float r = sigmoidf_(gr);
    float u = sigmoidf_(gu);
    float n = tanhf(gi + r*gh);
    upd[i] = (1.f-u)*n + u*hprevf[i];
}

// fused gather for both hops; map entry valid iff msg_nids[mi]==sid (no map init required)
__global__ void k_gatherf(const int* seed1,const int* seed0,const int* map,const int* msg_nids,
                          const float* memory,const float* upd,
                          unsigned short* hb1, unsigned short* acat1,
                          unsigned short* hb0, unsigned short* acat0){
    int i = blockIdx.x*256 + threadIdx.x;
    const int total1 = N1C*D;
    int li; const int* seed; unsigned short* hb; unsigned short* acat; int ldav, hoff;
    if(i < total1){ li=i; seed=seed1; hb=hb1; acat=acat1; ldav=584; hoff=456; }
    else { li = i - total1; if(li >= N0C*D) return; seed=seed0; hb=hb0; acat=acat0; ldav=840; hoff=712; }
    int row = li>>7, c = li&127;
    int sid = seed[row];
    int mi = map[sid];
    bool valid = ((unsigned)mi < (unsigned)MC) && (msg_nids[mi] == sid);
    float v = valid ? upd[(size_t)mi*D + c] : memory[(size_t)sid*D + c];
    unsigned short u = f2b(v);
    hb[li] = u;
    acat[(size_t)row*ldav + hoff + c] = u;
}

// ---------- bf16 MFMA GEMM, reg-prefetch pipelined, optional split-K ----------
// SPLITK>1: writes f32 partials [z][M][ldc], no bias/relu
template<int BM, int SPLITK, bool RELU, bool OUTF32>
__global__ __launch_bounds__(256) void k_gmm(const unsigned short* A, int lda,
                                             const unsigned short* B, int ldb,
                                             const float* bias, void* Cp, int ldc,
                                             int K, int N, int M){
    constexpr int ASTR = 72;
    constexpr int BSTR = 72;
    constexpr int RPW = BM/4;
    constexpr int RT  = RPW/16;
    constexpr int AIT = BM/32;
    __shared__ unsigned short As[BM*ASTR];
    __shared__ unsigned short Bs[64*BSTR];
    int t = threadIdx.x;
    int wave = t>>6, lane = t&63;
    int l15 = lane&15, l4 = lane>>4;
    int m0 = blockIdx.y*BM, n0 = blockIdx.x*64;
    int ntiles = (K+63)>>6;
    int tbeg, tend;
    if(SPLITK==1){ tbeg=0; tend=ntiles; }
    else {
        int tper = (ntiles + SPLITK-1)/SPLITK;
        tbeg = blockIdx.z*tper;
        tend = min(ntiles, tbeg+tper);
    }
    f32x4 acc[RT][4];
    #pragma unroll
    for(int rt=0;rt<RT;++rt)
        #pragma unroll
        for(int ct=0;ct<4;++ct) acc[rt][ct] = (f32x4){0.f,0.f,0.f,0.f};

    uint4 apre[AIT]; unsigned short bpre[16];
    auto loadA = [&](int kt){
        int k0 = kt<<6;
        #pragma unroll
        for(int i=0;i<AIT;++i){
            int idx = t + i*256;
            int row = idx>>3; int kc = (idx&7)*8;
            uint4 v = {0u,0u,0u,0u};
            if(k0+kc < K) v = *(const uint4*)(A + (size_t)(m0+row)*lda + k0 + kc);
            apre[i] = v;
        }
    };
    auto loadB = [&](int kt){
        int k0 = kt<<6;
        int n = t&63; int kb = (t>>6)*16;
        int ng = n0+n;
        #pragma unroll
        for(int j=0;j<16;++j){
            int kg = k0 + kb + j;
            bpre[j] = (kg<K && ng<N) ? B[(size_t)kg*ldb + ng] : (unsigned short)0;
        }
    };
    auto stash = [&](){
        #pragma unroll
        for(int i=0;i<AIT;++i){
            int idx = t + i*256;
            int row = idx>>3; int kc = (idx&7)*8;
            *(uint4*)&As[row*ASTR + kc] = apre[i];
        }
        int n = t&63; int kb = (t>>6)*16;
        #pragma unroll
        for(int j=0;j<16;++j) Bs[n*BSTR + kb + j] = bpre[j];
    };

    loadA(tbeg); loadB(tbeg);
    for(int kt=tbeg; kt<tend; ++kt){
        stash();
        __syncthreads();
        if(kt+1 < tend){ loadA(kt+1); loadB(kt+1); }
        #pragma unroll
        for(int kk=0; kk<64; kk+=32){
            short8v bfr[4];
            #pragma unroll
            for(int ct=0;ct<4;++ct)
                bfr[ct] = *(const short8v*)&Bs[(ct*16+l15)*BSTR + kk + l4*8];
            #pragma unroll
            for(int rt=0;rt<RT;++rt){
                short8v afr = *(const short8v*)&As[(wave*RPW + rt*16 + l15)*ASTR + kk + l4*8];
                #pragma unroll
                for(int ct=0;ct<4;++ct)
                    acc[rt][ct] = __builtin_amdgcn_mfma_f32_16x16x32_bf16(afr, bfr[ct], acc[rt][ct], 0,0,0);
            }
        }
        __syncthreads();
    }
    #pragma unroll
    for(int rt=0;rt<RT;++rt){
        #pragma unroll
        for(int ct=0;ct<4;++ct){
            int col = n0 + ct*16 + l15;
            if(col < N){
                #pragma unroll
                for(int r=0;r<4;++r){
                    int row = m0 + wave*RPW + rt*16 + l4*4 + r;
                    if(SPLITK==1){
                        float v = acc[rt][ct][r] + bias[col];
                        if(RELU) v = fmaxf(v, 0.f);
                        if(OUTF32) ((float*)Cp)[(size_t)row*ldc + col] = v;
                        else ((unsigned short*)Cp)[(size_t)row*ldc + col] = f2b(v);
                    } else {
                        ((float*)Cp)[((size_t)blockIdx.z*M + row)*ldc + col] = acc[rt][ct][r];
                    }
                }
            }
        }
    }
}

// split-K reduce + bias (+relu); N power of two
template<int SPL, bool RELU, bool OUTF32>
__global__ void k_kred(const float* part, int M, int N, const float* bias, void* out){
    int i = blockIdx.x*256 + threadIdx.x;
    if(i >= M*N) return;
    int col = i & (N-1);
    float v = bias[col];
    #pragma unroll
    for(int z=0;z<SPL;++z) v += part[(size_t)z*M*N + i];
    if(RELU) v = fmaxf(v, 0.f);
    if(OUTF32) ((float*)out)[i] = v;
    else ((unsigned short*)out)[i] = f2b(v);
}

// fused scores + masked softmax + av.
// Round-5 structure: kin lives in VGPRs, PINNED with empty inline asm so the
// compiler cannot rematerialize it (round 2: VGPR=44 + FETCH +24.5MB proved remat
// = phase-1 executed twice; round 4: LDS staging fixed FETCH but serialized the
// critical path through ds_write/ds_read, 101us vs 75us). __launch_bounds__(256,4)
// gives a 128-VGPR budget; kin4 = 40 VGPRs fits. Phase 1 branchless with masked
// loads gated to k=0's addresses (L1 hits); dot/butterfly/AV skip masked k via
// wave-uniform SGPR branches (bit-exact: masked softmax weight is exactly 0).
template<int K, int CMIN, int S4, int NPW>
__global__ __launch_bounds__(256,4) void k_attn(const unsigned short* __restrict__ qwb,
    unsigned short* __restrict__ avout, int ldav,
    const float* __restrict__ times, const float* __restrict__ nbr_times,
    const float* __restrict__ nbr_feats,
    const int* __restrict__ nbr_mask, const int* __restrict__ nbr_local,
    const unsigned short* __restrict__ zbuf,
    const float* __restrict__ time_w, const float* __restrict__ time_b){
    constexpr int SPAN = KIN - CMIN;
    constexpr int QSTR = SPAN + 4;
    constexpr int QLD  = 2*QSTR;
    int wv = __builtin_amdgcn_readfirstlane(blockIdx.x*4 + (threadIdx.x>>6));
    int lane = threadIdx.x & 63;

    float4 tw4[S4], tb4[S4];
    #pragma unroll
    for(int s=0;s<S4;++s){
        int c = CMIN + s*256 + lane*4;
        if(c >= D+E && c < KIN){
            tw4[s] = *(const float4*)(time_w + (c-(D+E)));
            tb4[s] = *(const float4*)(time_b + (c-(D+E)));
        } else {
            tw4[s] = make_float4(0.f,0.f,0.f,0.f);
            tb4[s] = make_float4(0.f,0.f,0.f,0.f);
        }
    }

    #pragma unroll
    for(int i=0;i<NPW;++i){
        int n = wv*NPW + i;
        const unsigned short* qrow = qwb + (size_t)n*QLD;
        // wave-uniform scalar loads (SGPRs)
        float tn = times[n];
        int   mk[K]; float tk[K]; int nl[K];
        #pragma unroll
        for(int k=0;k<K;++k){
            mk[k] = nbr_mask [(size_t)n*K + k];
            tk[k] = nbr_times[(size_t)n*K + k];
            nl[k] = (CMIN==0) ? nbr_local[(size_t)n*K + k] : 0;
        }

        float4 qw4[NHD][S4]; float qb[NHD];
        #pragma unroll
        for(int h=0;h<NHD;++h){
            qb[h] = b2f(qrow[h*QSTR + SPAN]);
            #pragma unroll
            for(int s=0;s<S4;++s){
                int cl = s*256 + lane*4;
                float4 v = make_float4(0.f,0.f,0.f,0.f);
                if(cl < SPAN){
                    uint2 wq = *(const uint2*)(qrow + h*QSTR + cl);
                    v.x = __uint_as_float(wq.x<<16);
                    v.y = __uint_as_float(wq.x & 0xffff0000u);
                    v.z = __uint_as_float(wq.y<<16);
                    v.w = __uint_as_float(wq.y & 0xffff0000u);
                }
                pin4(v);
                qw4[h][s] = v;
            }
        }

        // phase 1: materialize kin for ALL neighbors into pinned registers.
        // Branchless; masked k reads k=0's addresses (always active) -> L1 hits,
        // values never consumed (dot/butterfly/AV skip masked k).
        float4 kin4[K][S4];
        #pragma unroll
        for(int k=0;k<K;++k){
            int gk = (mk[k] > 0) ? k : 0;
            float dt = tn - tk[gk];
            const float* ef = nbr_feats + (size_t)(n*K+gk)*E;
            const unsigned short* zf = (CMIN==0) ?
                (zbuf + (size_t)(nl[gk] - N0C)*D) : (const unsigned short*)0;
            #pragma unroll
            for(int s=0;s<S4;++s){
                int c = CMIN + s*256 + lane*4;
                float4 kv = make_float4(0.f,0.f,0.f,0.f);
                if(c < KIN){
                    if(CMIN==0 && c < D){
                        uint2 wz = *(const uint2*)(zf + c);
                        kv.x = __uint_as_float(wz.x<<16);
                        kv.y = __uint_as_float(wz.x & 0xffff0000u);
                        kv.z = __uint_as_float(wz.y<<16);
                        kv.w = __uint_as_float(wz.y & 0xffff0000u);
                    } else if(c < D+E){
                        kv = *(const float4*)(ef + (c-D));
                    } else {
                        kv.x = __cosf(dt*tw4[s].x + tb4[s].x);
                        kv.y = __cosf(dt*tw4[s].y + tb4[s].y);
                        kv.z = __cosf(dt*tw4[s].z + tb4[s].z);
                        kv.w = __cosf(dt*tw4[s].w + tb4[s].w);
                    }
                }
                pin4(kv);                 // forbid remat: value is now opaque
                kin4[k][s] = kv;
            }
        }

        // phase 2: lane-partial dot products, active-only (uniform branch, reg reads)
        float p0[K], p1[K];
        #pragma unroll
        for(int k=0;k<K;++k){ p0[k]=0.f; p1[k]=0.f; }
        #pragma unroll
        for(int k=0;k<K;++k){
            if(mk[k] > 0){
                float a0 = 0.f, a1 = 0.f;
                #pragma unroll
                for(int s=0;s<S4;++s){
                    float4 kv = kin4[k][s];
                    a0 += kv.x*qw4[0][s].x + kv.y*qw4[0][s].y + kv.z*qw4[0][s].z + kv.w*qw4[0][s].w;
                    a1 += kv.x*qw4[1][s].x + kv.y*qw4[1][s].y + kv.z*qw4[1][s].z + kv.w*qw4[1][s].w;
                }
                p0[k] = a0; p1[k] = a1;
            }
        }

        // phase 3: interleaved butterfly, active-only — independent chains per step
        #pragma unroll
        for(int off=32; off; off>>=1){
            #pragma unroll
            for(int k=0;k<K;++k){
                if(mk[k] > 0){
                    p0[k] += __shfl_xor(p0[k], off);
                    p1[k] += __shfl_xor(p1[k], off);
                }
            }
        }

        float sval[NHD][K];
        #pragma unroll
        for(int k=0;k<K;++k){
            bool act = mk[k] > 0;
            sval[0][k] = act ? (p0[k] + qb[0])*0.125f : -1e9f;
            sval[1][k] = act ? (p1[k] + qb[1])*0.125f : -1e9f;
        }
        #pragma unroll
        for(int h=0;h<NHD;++h){
            float mx = -1e30f;
            #pragma unroll
            for(int k=0;k<K;++k) mx = fmaxf(mx, sval[h][k]);
            float z=0.f;
            #pragma unroll
            for(int k=0;k<K;++k){ float e = __expf(sval[h][k]-mx); sval[h][k]=e; z+=e; }
            float inv = 1.f/z;
            #pragma unroll
            for(int k=0;k<K;++k) sval[h][k]*=inv;
        }

        // AV: s-outer so each kin reg serves both heads; active-only (exact: masked w==0)
        #pragma unroll
        for(int s=0;s<S4;++s){
            int cl = s*256 + lane*4;
            if(cl < SPAN){
                float a00=0.f,a01=0.f,a02=0.f,a03=0.f;
                float a10=0.f,a11=0.f,a12=0.f,a13=0.f;
                #pragma unroll
                for(int k=0;k<K;++k){
                    if(mk[k] > 0){
                        float4 kv = kin4[k][s];
                        float w0 = sval[0][k], w1 = sval[1][k];
                        a00 += w0*kv.x; a01 += w0*kv.y; a02 += w0*kv.z; a03 += w0*kv.w;
                        a10 += w1*kv.x; a11 += w1*kv.y; a12 += w1*kv.z; a13 += w1*kv.w;
                    }
                }
                uint2 o0, o1;
                o0.x = (unsigned int)f2b(a00) | ((unsigned int)f2b(a01)<<16);
                o0.y = (unsigned int)f2b(a02) | ((unsigned int)f2b(a03)<<16);
                o1.x = (unsigned int)f2b(a10) | ((unsigned int)f2b(a11)<<16);
                o1.y = (unsigned int)f2b(a12) | ((unsigned int)f2b(a13)<<16);
                *(uint2*)(avout + (size_t)n*ldav + cl)        = o0;
                *(uint2*)(avout + (size_t)n*ldav + SPAN + cl) = o1;
            }
        }
    }
}

// link prediction
__global__ __launch_bounds__(128) void k_linkpred(const float* z0,
      const int* src,const int* dst,const int* neg,
      const float* Ws,const float* bs,const float* Wd,const float* bd,
      const float* Wo,const float* bo, float* out){
    __shared__ float zs[D], zd[D], zn[D];
    __shared__ float red[4];
    int b = blockIdx.x; int d = threadIdx.x;
    zs[d] = z0[(size_t)src[b]*D + d];
    zd[d] = z0[(size_t)dst[b]*D + d];
    zn[d] = z0[(size_t)neg[b]*D + d];
    __syncthreads();
    float ss=0.f, sdd=0.f, snn=0.f;
    for(int c=0;c<D;++c){
        float w1 = Ws[c*D + d], w2 = Wd[c*D + d];
        ss  += zs[c]*w1; sdd += zd[c]*w2; snn += zn[c]*w2;
    }
    float bb = bs[d] + bd[d];
    float h1 = fmaxf(ss + sdd + bb, 0.f);
    float h2 = fmaxf(ss + snn + bb, 0.f);
    float w = Wo[d];
    float v1 = h1*w, v2 = h2*w;
    #pragma unroll
    for(int off=32; off; off>>=1){ v1 += __shfl_xor(v1,off); v2 += __shfl_xor(v2,off); }
    int wid = d>>6;
    if((d&63)==0){ red[wid*2]=v1; red[wid*2+1]=v2; }
    __syncthreads();
    if(d==0){
        out[b]       = sigmoidf_(red[0]+red[2] + bo[0]);
        out[BSZ + b] = sigmoidf_(red[1]+red[3] + bo[0]);
    }
}

extern "C" void kernel_launch(void* const* d_in, const int* in_sizes, int n_in,
                              void* d_out, int out_size, void* d_ws, size_t ws_size,
                              hipStream_t stream) {
    const float* memory  = (const float*)d_in[0];
    const float* time_w  = (const float*)d_in[1];
    const float* time_b  = (const float*)d_in[2];
    const float* gWih    = (const float*)d_in[3];
    const float* gbih    = (const float*)d_in[4];
    const float* gWhh    = (const float*)d_in[5];
    const float* gbhh    = (const float*)d_in[6];
    const float* Wq0=(const float*)d_in[7],  *bq0=(const float*)d_in[8];
    const float* Wk0=(const float*)d_in[9],  *bk0=(const float*)d_in[10];
    const float* Wv0=(const float*)d_in[11], *bv0=(const float*)d_in[12];
    const float* Wo0=(const float*)d_in[13], *bo0=(const float*)d_in[14];
    const float* Wq1=(const float*)d_in[15], *bq1=(const float*)d_in[16];
    const float* Wk1=(const float*)d_in[17], *bk1=(const float*)d_in[18];
    const float* Wv1=(const float*)d_in[19], *bv1=(const float*)d_in[20];
    const float* Wo1=(const float*)d_in[21], *bo1=(const float*)d_in[22];
    const float* lpWs=(const float*)d_in[23], *lpbs=(const float*)d_in[24];
    const float* lpWd=(const float*)d_in[25], *lpbd=(const float*)d_in[26];
    const float* lpWo=(const float*)d_in[27], *lpbo=(const float*)d_in[28];
    const float* msgs    = (const float*)d_in[29];
    const float* times0  = (const float*)d_in[30];
    const float* ntimes0 = (const float*)d_in[31];
    const float* nfeats0 = (const float*)d_in[32];
    const float* times1  = (const float*)d_in[33];
    const float* ntimes1 = (const float*)d_in[34];
    const float* nfeats1 = (const float*)d_in[35];
    const int* msg_nids  = (const int*)d_in[36];
    const int* seed0     = (const int*)d_in[37];
    const int* seed1     = (const int*)d_in[38];
    const int* nbr_local0= (const int*)d_in[39];
    const int* nbr_mask0 = (const int*)d_in[40];
    const int* nbr_mask1 = (const int*)d_in[41];
    const int* src       = (const int*)d_in[42];
    const int* dst       = (const int*)d_in[43];
    const int* neg       = (const int*)d_in[44];

    char* ws = (char*)d_ws;
    size_t off = 0;
    auto alloc = [&](size_t bytes)->char*{
        char* p = ws + off;
        off += (bytes + 255) & ~(size_t)255;
        return p;
    };
    int*   map   = (int*)  alloc((size_t)NNC*4);
    float* upd   = (float*)alloc((size_t)MC*D*4);
    unsigned short* hb1   = (unsigned short*)alloc((size_t)N1C*D*2);
    unsigned short* qwb1  = (unsigned short*)alloc((size_t)N1C*464*2);
    unsigned short* acat1 = (unsigned short*)alloc((size_t)N1C*584*2);
    unsigned short* zb1   = (unsigned short*)alloc((size_t)N1C*D*2);
    unsigned short* hb0   = (unsigned short*)alloc((size_t)N0C*D*2);
    unsigned short* qwb0  = (unsigned short*)alloc((size_t)N0C*720*2);
    unsigned short* acat0 = (unsigned short*)alloc((size_t)N0C*840*2);
    float* z0    = (float*)alloc((size_t)N0C*D*4);
    float* qc0   = (float*)alloc(512);
    float* qc1   = (float*)alloc(512);
    float* cb0   = (float*)alloc(512);
    float* cb1   = (float*)alloc(512);
    unsigned short* WFb0 = (unsigned short*)alloc((size_t)D*720*2);
    unsigned short* WFb1 = (unsigned short*)alloc((size_t)D*464*2);
    float* cF0   = (float*)alloc((size_t)720*4);
    float* cF1   = (float*)alloc((size_t)464*4);
    unsigned short* Bcat1 = (unsigned short*)alloc((size_t)584*D*2);
    unsigned short* Bcat0 = (unsigned short*)alloc((size_t)840*D*2);
    unsigned short* gA    = (unsigned short*)alloc((size_t)MC*GKP*2);
    unsigned short* gB    = (unsigned short*)alloc((size_t)GK*GN*2);
    float* gBias = (float*)alloc((size_t)GN*4);
    float* hprevf= (float*)alloc((size_t)MC*D*4);
    float* part  = (float*)alloc((size_t)2*N1C*D*4);   // 31.5 MB, shared by all split-K
    float* outp = (float*)d_out;

    // precompute (gru bias fused in)
    k_pre_small<<<1,512,0,stream>>>(time_b, Wq0,bq0,Wq1,bq1, bv0,Wo0,bo0, bv1,Wo1,bo1,
                                    gbih, gbhh, gBias, qc0,qc1,cb0,cb1);
    k_wf<<<720,128,0,stream>>>(Wq0,Wk0,bk0,qc0, WFb0,cF0, 0);
    k_wf<<<464,128,0,stream>>>(Wq1,Wk1,bk1,qc1, WFb1,cF1, 128);
    k_bcat<<<584,128,0,stream>>>(Wv1, Wo1, Bcat1, 128);
    k_bcat<<<840,128,0,stream>>>(Wv0, Wo0, Bcat0, 0);
    k_gruB<<<dim3(10,8),256,0,stream>>>(gWih, gWhh, gB);

    // GRU memory update via split-K MFMA GEMM + fused reduce/gates (map scatter fused in acvt)
    k_acvt<<<(MC*GKP+255)/256,256,0,stream>>>(msgs, memory, msg_nids, gA, hprevf, map);
    k_gmm<128,3,false,true><<<dim3(GN/64, MC/128, 3),256,0,stream>>>(gA,GKP, gB,GN, gBias, part,GN, GK, GN, MC);
    k_gates3<<<(MC*D+255)/256,256,0,stream>>>(part, gBias, hprevf, upd);

    // gather node states (both hops) -> bf16
    k_gatherf<<<((N1C+N0C)*D)/256,256,0,stream>>>(seed1, seed0, map, msg_nids, memory, upd,
                                                  hb1, acat1, hb0, acat0);

    // GEMM1 (MFMA): qw = h @ WF + cF
    k_gmm<128,1,false,false><<<dim3(8,  N1C/128),256,0,stream>>>(hb1,128, WFb1,464, cF1, qwb1,464, 128, 464, N1C);
    k_gmm<128,1,false,false><<<dim3(12, N0C/128),256,0,stream>>>(hb0,128, WFb0,720, cF0, qwb0,720, 128, 720, N0C);

    // hop 1 attention (7680 blocks)
    k_attn<K1C,128,1,1><<<N1C/4,256,0,stream>>>(qwb1, acat1, 584, times1, ntimes1, nfeats1,
                                                nbr_mask1, (const int*)0, (const unsigned short*)0,
                                                time_w, time_b);
    // GEMM2 hop1: split-K=2 (960 blocks) + reduce -> bf16 zb1
    k_gmm<128,2,true,false><<<dim3(2, N1C/128, 2),256,0,stream>>>(acat1,584, Bcat1,D, cb1, part,D, 584, D, N1C);
    k_kred<2,true,false><<<(N1C*D+255)/256,256,0,stream>>>(part, N1C, D, cb1, zb1);

    // hop 0 attention (1536 blocks)
    k_attn<K0C,0,2,1><<<N0C/4,256,0,stream>>>(qwb0, acat0, 840, times0, ntimes0, nfeats0,
                                              nbr_mask0, nbr_local0, zb1,
                                              time_w, time_b);
    // GEMM2 hop0: BM=64, split-K=4 (768 blocks) + reduce -> f32 z0
    k_gmm<64,4,true,true><<<dim3(2, N0C/64, 4),256,0,stream>>>(acat0,840, Bcat0,D, cb0, part,D, 840, D, N0C);
    k_kred<4,true,true><<<(N0C*D+255)/256,256,0,stream>>>(part, N0C, D, cb0, z0);

    // link prediction
    k_linkpred<<<BSZ,128,0,stream>>>(z0, src,dst,neg, lpWs,lpbs,lpWd,lpbd, lpWo,lpbo, outp);
}

// Round 11
// 543.908 us; speedup vs baseline: 1.0865x; 1.0726x over previous
//
#include <hip/hip_runtime.h>
#include <math.h>

// ---- problem constants ----
#define D    128
#define TT   128
#define E    100
#define NHD  2
#define BSZ  2048
#define N0C  6144
#define K0C  5
#define N1C  30720
#define K1C  10
#define NNC  200000
#define MC   4096
#define MSG  484
#define KIN  356        // D+E+T
#define GK   612        // MSG + D (GRU GEMM K)
#define GKP  616        // padded to 8
#define GN   512        // GRU GEMM N (256 rz-sum + 128 in + 128 hn)

typedef __attribute__((ext_vector_type(8))) short short8v;   // 8 bf16 (4 VGPRs)
typedef __attribute__((ext_vector_type(4))) float f32x4;

__device__ __forceinline__ float sigmoidf_(float x){ return 1.f/(1.f+__expf(-x)); }
__device__ __forceinline__ unsigned short f2b(float f){
    unsigned int x = __float_as_uint(f);
    unsigned int r = (x + 0x7fffu + ((x>>16)&1u)) >> 16;
    return (unsigned short)r;
}
__device__ __forceinline__ float b2f(unsigned short u){
    return __uint_as_float(((unsigned int)u)<<16);
}

// ---------- precompute: qc (time-const query bias), cb (fused out bias), gru bias ----------
__global__ void k_pre_small(const float* time_b,
                            const float* Wq0,const float* bq0,const float* Wq1,const float* bq1,
                            const float* bv0,const float* Wo0,const float* bo0,
                            const float* bv1,const float* Wo1,const float* bo1,
                            const float* bih,const float* bhh,float* gBias,
                            float* qc0, float* qc1, float* cb0, float* cb1){
    __shared__ float cosb[TT];
    int j = threadIdx.x; // 512 threads
    if(j < TT) cosb[j] = cosf(time_b[j]);
    __syncthreads();
    if(j < 128){
        float a0=bq0[j], a1=bq1[j];
        for(int t=0;t<TT;++t){ a0 += cosb[t]*Wq0[(D+t)*D + j]; a1 += cosb[t]*Wq1[(D+t)*D + j]; }
        qc0[j]=a0; qc1[j]=a1;
        float c0=bo0[j], c1=bo1[j];
        for(int jp=0;jp<D;++jp){ c0 += bv0[jp]*Wo0[jp*D + j]; c1 += bv1[jp]*Wo1[jp*D + j]; }
        cb0[j]=c0; cb1[j]=c1;
    }
    if(j < GN){
        float v;
        if(j < 256)      v = bih[j] + bhh[j];
        else if(j < 384) v = bih[j];
        else             v = bhh[j-128];
        gBias[j] = v;
    }
}

// WF (bf16), head h at col h*hstr + cl, cl in [0,span] (cl==span is qb col = bk-derived)
// hstr = span + 4 (pad cols zeroed); width = 2*hstr
__global__ void k_wf(const float* Wq,const float* Wk,const float* bk,const float* qc,
                     unsigned short* WF, float* cF, int cmin){
    int span = 356 - cmin;
    int hstr = span + 4;
    int width = 2*hstr;
    int idx = blockIdx.x;            // [0, 2*hstr)
    int h = idx / hstr; int cl = idx % hstr;
    int k = threadIdx.x;
    if(cl > span){
        WF[(size_t)k*width + idx] = (unsigned short)0;
        if(k==0) cF[idx] = 0.f;
        return;
    }
    int c = cmin + cl;
    float a = 0.f;
    for(int d=0; d<64; ++d){
        float wkv = (c < KIN) ? Wk[c*D + h*64+d] : bk[h*64+d];
        a += Wq[k*D + h*64+d] * wkv;
    }
    WF[(size_t)k*width + idx] = f2b(a);
    if(k==0){
        float s=0.f;
        for(int d=0; d<64; ++d){
            float wkv = (c < KIN) ? Wk[c*D + h*64+d] : bk[h*64+d];
            s += qc[h*64+d]*wkv;
        }
        cF[idx] = s;
    }
}

// Bcat (bf16): rows [0, 2*span) = fused Wvo rows; rows [2*span, +128) = Wo bottom half
__global__ void k_bcat(const float* Wv, const float* Wo, unsigned short* Bcat, int cmin){
    int span = KIN - cmin; int rows = 2*span;
    int r = blockIdx.x; int j = threadIdx.x;
    float a;
    if(r < rows){
        int h = r/span; int c = cmin + (r - h*span);
        a = 0.f;
        for(int d=0; d<64; ++d) a += Wv[c*D + h*64+d] * Wo[(h*64+d)*D + j];
    } else {
        a = Wo[(size_t)(D + (r - rows))*D + j];
    }
    Bcat[(size_t)r*D + j] = f2b(a);
}

// ---------- GRU as GEMM: packed B (612 x 512 bf16) via coalesced LDS transpose ----------
__global__ __launch_bounds__(256) void k_gruB(const float* Wih, const float* Whh, unsigned short* B){
    __shared__ float tile[64][65];
    int rb = blockIdx.x*64;
    int jb = blockIdx.y*64;
    int t = threadIdx.x;
    int rr = t&63, jj0 = t>>6;
    #pragma unroll
    for(int i=0;i<16;++i){
        int jj = jj0 + i*4;
        int j = jb + jj; int r = rb + rr;
        float v = 0.f;
        if(r < GK){
            if(j < 256)      v = (r<MSG)? Wih[(size_t)j*MSG+r] : Whh[(size_t)j*D + (r-MSG)];
            else if(j < 384) v = (r<MSG)? Wih[(size_t)j*MSG+r] : 0.f;
            else             v = (r<MSG)? 0.f : Whh[(size_t)(j-128)*D + (r-MSG)];
        }
        tile[jj][rr] = v;
    }
    __syncthreads();
    int jw = t&63, rr0 = t>>6;
    #pragma unroll
    for(int i=0;i<16;++i){
        int rr2 = rr0 + i*4;
        int r = rb + rr2;
        if(r < GK) B[(size_t)r*GN + jb + jw] = f2b(tile[jw][rr2]);
    }
}
// A-matrix convert + map scatter fused (map entries validated on read, no init needed)
__global__ void k_acvt(const float* msgs, const float* memory, const int* msg_nids,
                       unsigned short* ab, float* hprevf, int* map){
    int i = blockIdx.x*256 + threadIdx.x;
    if(i >= MC*GKP) return;
    int row = i / GKP; int c = i - row*GKP;
    if(c == 0) map[msg_nids[row]] = row;
    float v;
    if(c < MSG) v = msgs[(size_t)row*MSG + c];
    else if(c < GK){ int d = c-MSG; v = memory[(size_t)msg_nids[row]*D + d]; hprevf[row*D+d] = v; }
    else v = 0.f;
    ab[i] = f2b(v);
}
// fused split-K reduce + gates: upd = (1-u)*tanh(inn + r*hn) + u*h
__global__ void k_gates3(const float* part, const float* bias, const float* hprevf, float* upd){
    int i = blockIdx.x*256 + threadIdx.x;
    if(i >= MC*D) return;
    int row = i>>7, d = i&127;
    const float* p = part + (size_t)row*GN;
    const size_t S = (size_t)MC*GN;
    float gr = p[d]     + p[S+d]     + p[2*S+d]     + bias[d];
    float gu = p[128+d] + p[S+128+d] + p[2*S+128+d] + bias[128+d];
    float gi = p[256+d] + p[S+256+d] + p[2*S+256+d] + bias[256+d];
    float gh = p[384+d] + p[S+384+d] + p[2*S+384+d] + bias[384+d];
    float r = sigmoidf_(gr);
    float u = sigmoidf_(gu);
    float n = tanhf(gi + r*gh);
    upd[i] = (1.f-u)*n + u*hprevf[i];
}

// fused gather for both hops; map entry valid iff msg_nids[mi]==sid (no map init required)
__global__ void k_gatherf(const int* seed1,const int* seed0,const int* map,const int* msg_nids,
                          const float* memory,const float* upd,
                          unsigned short* hb1, unsigned short* acat1,
                          unsigned short* hb0, unsigned short* acat0){
    int i = blockIdx.x*256 + threadIdx.x;
    const int total1 = N1C*D;
    int li; const int* seed; unsigned short* hb; unsigned short* acat; int ldav, hoff;
    if(i < total1){ li=i; seed=seed1; hb=hb1; acat=acat1; ldav=584; hoff=456; }
    else { li = i - total1; if(li >= N0C*D) return; seed=seed0; hb=hb0; acat=acat0; ldav=840; hoff=712; }
    int row = li>>7, c = li&127;
    int sid = seed[row];
    int mi = map[sid];
    bool valid = ((unsigned)mi < (unsigned)MC) && (msg_nids[mi] == sid);
    float v = valid ? upd[(size_t)mi*D + c] : memory[(size_t)sid*D + c];
    unsigned short u = f2b(v);
    hb[li] = u;
    acat[(size_t)row*ldav + hoff + c] = u;
}

// ---------- bf16 MFMA GEMM, reg-prefetch pipelined, optional split-K ----------
// SPLITK>1: writes f32 partials [z][M][ldc], no bias/relu
template<int BM, int SPLITK, bool RELU, bool OUTF32>
__global__ __launch_bounds__(256) void k_gmm(const unsigned short* A, int lda,
                                             const unsigned short* B, int ldb,
                                             const float* bias, void* Cp, int ldc,
                                             int K, int N, int M){
    constexpr int ASTR = 72;
    constexpr int BSTR = 72;
    constexpr int RPW = BM/4;
    constexpr int RT  = RPW/16;
    constexpr int AIT = BM/32;
    __shared__ unsigned short As[BM*ASTR];
    __shared__ unsigned short Bs[64*BSTR];
    int t = threadIdx.x;
    int wave = t>>6, lane = t&63;
    int l15 = lane&15, l4 = lane>>4;
    int m0 = blockIdx.y*BM, n0 = blockIdx.x*64;
    int ntiles = (K+63)>>6;
    int tbeg, tend;
    if(SPLITK==1){ tbeg=0; tend=ntiles; }
    else {
        int tper = (ntiles + SPLITK-1)/SPLITK;
        tbeg = blockIdx.z*tper;
        tend = min(ntiles, tbeg+tper);
    }
    f32x4 acc[RT][4];
    #pragma unroll
    for(int rt=0;rt<RT;++rt)
        #pragma unroll
        for(int ct=0;ct<4;++ct) acc[rt][ct] = (f32x4){0.f,0.f,0.f,0.f};

    uint4 apre[AIT]; unsigned short bpre[16];
    auto loadA = [&](int kt){
        int k0 = kt<<6;
        #pragma unroll
        for(int i=0;i<AIT;++i){
            int idx = t + i*256;
            int row = idx>>3; int kc = (idx&7)*8;
            uint4 v = {0u,0u,0u,0u};
            if(k0+kc < K) v = *(const uint4*)(A + (size_t)(m0+row)*lda + k0 + kc);
            apre[i] = v;
        }
    };
    auto loadB = [&](int kt){
        int k0 = kt<<6;
        int n = t&63; int kb = (t>>6)*16;
        int ng = n0+n;
        #pragma unroll
        for(int j=0;j<16;++j){
            int kg = k0 + kb + j;
            bpre[j] = (kg<K && ng<N) ? B[(size_t)kg*ldb + ng] : (unsigned short)0;
        }
    };
    auto stash = [&](){
        #pragma unroll
        for(int i=0;i<AIT;++i){
            int idx = t + i*256;
            int row = idx>>3; int kc = (idx&7)*8;
            *(uint4*)&As[row*ASTR + kc] = apre[i];
        }
        int n = t&63; int kb = (t>>6)*16;
        #pragma unroll
        for(int j=0;j<16;++j) Bs[n*BSTR + kb + j] = bpre[j];
    };

    loadA(tbeg); loadB(tbeg);
    for(int kt=tbeg; kt<tend; ++kt){
        stash();
        __syncthreads();
        if(kt+1 < tend){ loadA(kt+1); loadB(kt+1); }
        #pragma unroll
        for(int kk=0; kk<64; kk+=32){
            short8v bfr[4];
            #pragma unroll
            for(int ct=0;ct<4;++ct)
                bfr[ct] = *(const short8v*)&Bs[(ct*16+l15)*BSTR + kk + l4*8];
            #pragma unroll
            for(int rt=0;rt<RT;++rt){
                short8v afr = *(const short8v*)&As[(wave*RPW + rt*16 + l15)*ASTR + kk + l4*8];
                #pragma unroll
                for(int ct=0;ct<4;++ct)
                    acc[rt][ct] = __builtin_amdgcn_mfma_f32_16x16x32_bf16(afr, bfr[ct], acc[rt][ct], 0,0,0);
            }
        }
        __syncthreads();
    }
    #pragma unroll
    for(int rt=0;rt<RT;++rt){
        #pragma unroll
        for(int ct=0;ct<4;++ct){
            int col = n0 + ct*16 + l15;
            if(col < N){
                #pragma unroll
                for(int r=0;r<4;++r){
                    int row = m0 + wave*RPW + rt*16 + l4*4 + r;
                    if(SPLITK==1){
                        float v = acc[rt][ct][r] + bias[col];
                        if(RELU) v = fmaxf(v, 0.f);
                        if(OUTF32) ((float*)Cp)[(size_t)row*ldc + col] = v;
                        else ((unsigned short*)Cp)[(size_t)row*ldc + col] = f2b(v);
                    } else {
                        ((float*)Cp)[((size_t)blockIdx.z*M + row)*ldc + col] = acc[rt][ct][r];
                    }
                }
            }
        }
    }
}

// split-K reduce + bias (+relu); N power of two
template<int SPL, bool RELU, bool OUTF32>
__global__ void k_kred(const float* part, int M, int N, const float* bias, void* out){
    int i = blockIdx.x*256 + threadIdx.x;
    if(i >= M*N) return;
    int col = i & (N-1);
    float v = bias[col];
    #pragma unroll
    for(int z=0;z<SPL;++z) v += part[(size_t)z*M*N + i];
    if(RELU) v = fmaxf(v, 0.f);
    if(OUTF32) ((float*)out)[i] = v;
    else ((unsigned short*)out)[i] = f2b(v);
}

// fused scores + masked softmax + av — EXACT Round-2 structure (measured 75 us attn1,
// best total 559). Three alternatives measured worse: LDS staging (101 us, R4) and
// asm-pinned registers (105 us, R9 — volatile asm ordering serialized phase-1 loads).
// The compiler's remat-for-occupancy tradeoff (VGPR=44, phase-1 re-derived once) is
// the measured optimum of this structure; do not fight it.
template<int K, int CMIN, int S4, int NPW>
__global__ __launch_bounds__(256) void k_attn(const unsigned short* __restrict__ qwb,
    unsigned short* __restrict__ avout, int ldav,
    const float* __restrict__ times, const float* __restrict__ nbr_times,
    const float* __restrict__ nbr_feats,
    const int* __restrict__ nbr_mask, const int* __restrict__ nbr_local,
    const unsigned short* __restrict__ zbuf,
    const float* __restrict__ time_w, const float* __restrict__ time_b){
    constexpr int SPAN = KIN - CMIN;
    constexpr int QSTR = SPAN + 4;
    constexpr int QLD  = 2*QSTR;
    int wv = __builtin_amdgcn_readfirstlane(blockIdx.x*4 + (threadIdx.x>>6));
    int lane = threadIdx.x & 63;

    float4 tw4[S4], tb4[S4];
    #pragma unroll
    for(int s=0;s<S4;++s){
        int c = CMIN + s*256 + lane*4;
        if(c >= D+E && c < KIN){
            tw4[s] = *(const float4*)(time_w + (c-(D+E)));
            tb4[s] = *(const float4*)(time_b + (c-(D+E)));
        } else {
            tw4[s] = make_float4(0.f,0.f,0.f,0.f);
            tb4[s] = make_float4(0.f,0.f,0.f,0.f);
        }
    }

    #pragma unroll
    for(int i=0;i<NPW;++i){
        int n = wv*NPW + i;
        const unsigned short* qrow = qwb + (size_t)n*QLD;
        // wave-uniform scalar loads (SGPRs): time, masks, neighbor times, z indices
        float tn = times[n];
        int   mk[K]; float tk[K]; int nl[K];
        #pragma unroll
        for(int k=0;k<K;++k){
            mk[k] = nbr_mask [(size_t)n*K + k];
            tk[k] = nbr_times[(size_t)n*K + k];
            nl[k] = (CMIN==0) ? nbr_local[(size_t)n*K + k] : 0;
        }

        float4 qw4[NHD][S4]; float qb[NHD];
        #pragma unroll
        for(int h=0;h<NHD;++h){
            qb[h] = b2f(qrow[h*QSTR + SPAN]);
            #pragma unroll
            for(int s=0;s<S4;++s){
                int cl = s*256 + lane*4;
                float4 v = make_float4(0.f,0.f,0.f,0.f);
                if(cl < SPAN){
                    uint2 wq = *(const uint2*)(qrow + h*QSTR + cl);
                    v.x = __uint_as_float(wq.x<<16);
                    v.y = __uint_as_float(wq.x & 0xffff0000u);
                    v.z = __uint_as_float(wq.y<<16);
                    v.w = __uint_as_float(wq.y & 0xffff0000u);
                }
                qw4[h][s] = v;
            }
        }

        // phase 1: materialize kin for ALL neighbors (loads batched, no branches over k)
        float4 kin4[K][S4];
        #pragma unroll
        for(int k=0;k<K;++k){
            float dt = tn - tk[k];
            const float* ef = nbr_feats + (size_t)(n*K+k)*E;
            const unsigned short* zf = (CMIN==0) ?
                (zbuf + (size_t)(nl[k] - N0C)*D) : (const unsigned short*)0;
            #pragma unroll
            for(int s=0;s<S4;++s){
                int c = CMIN + s*256 + lane*4;
                float4 kv = make_float4(0.f,0.f,0.f,0.f);
                if(c < KIN){
                    if(CMIN==0 && c < D){
                        uint2 wz = *(const uint2*)(zf + c);
                        kv.x = __uint_as_float(wz.x<<16);
                        kv.y = __uint_as_float(wz.x & 0xffff0000u);
                        kv.z = __uint_as_float(wz.y<<16);
                        kv.w = __uint_as_float(wz.y & 0xffff0000u);
                    } else if(c < D+E){
                        kv = *(const float4*)(ef + (c-D));
                    } else {
                        kv.x = __cosf(dt*tw4[s].x + tb4[s].x);
                        kv.y = __cosf(dt*tw4[s].y + tb4[s].y);
                        kv.z = __cosf(dt*tw4[s].z + tb4[s].z);
                        kv.w = __cosf(dt*tw4[s].w + tb4[s].w);
                    }
                }
                kin4[k][s] = kv;
            }
        }

        // phase 2: lane-partial dot products for all (head, k)
        float p0[K], p1[K];
        #pragma unroll
        for(int k=0;k<K;++k){
            float a0 = 0.f, a1 = 0.f;
            #pragma unroll
            for(int s=0;s<S4;++s){
                float4 kv = kin4[k][s];
                a0 += kv.x*qw4[0][s].x + kv.y*qw4[0][s].y + kv.z*qw4[0][s].z + kv.w*qw4[0][s].w;
                a1 += kv.x*qw4[1][s].x + kv.y*qw4[1][s].y + kv.z*qw4[1][s].z + kv.w*qw4[1][s].w;
            }
            p0[k] = a0; p1[k] = a1;
        }

        // phase 3: one interleaved butterfly — 2K independent chains per step
        #pragma unroll
        for(int off=32; off; off>>=1){
            #pragma unroll
            for(int k=0;k<K;++k){
                p0[k] += __shfl_xor(p0[k], off);
                p1[k] += __shfl_xor(p1[k], off);
            }
        }

        float sval[NHD][K];
        #pragma unroll
        for(int k=0;k<K;++k){
            bool act = mk[k] > 0;
            sval[0][k] = act ? (p0[k] + qb[0])*0.125f : -1e9f;
            sval[1][k] = act ? (p1[k] + qb[1])*0.125f : -1e9f;
        }
        #pragma unroll
        for(int h=0;h<NHD;++h){
            float mx = -1e30f;
            #pragma unroll
            for(int k=0;k<K;++k) mx = fmaxf(mx, sval[h][k]);
            float z=0.f;
            #pragma unroll
            for(int k=0;k<K;++k){ float e = __expf(sval[h][k]-mx); sval[h][k]=e; z+=e; }
            float inv = 1.f/z;
            #pragma unroll
            for(int k=0;k<K;++k) sval[h][k]*=inv;
        }
        // AV: unconditional — masked weights are exactly 0
        #pragma unroll
        for(int h=0;h<NHD;++h)
          #pragma unroll
          for(int s=0;s<S4;++s){
            int cl = s*256 + lane*4;
            if(cl < SPAN){
                float v0=0.f,v1=0.f,v2=0.f,v3=0.f;
                #pragma unroll
                for(int k=0;k<K;++k){
                    float a = sval[h][k];
                    v0 += a*kin4[k][s].x; v1 += a*kin4[k][s].y;
                    v2 += a*kin4[k][s].z; v3 += a*kin4[k][s].w;
                }
                uint2 o;
                o.x = (unsigned int)f2b(v0) | ((unsigned int)f2b(v1)<<16);
                o.y = (unsigned int)f2b(v2) | ((unsigned int)f2b(v3)<<16);
                *(uint2*)(avout + (size_t)n*ldav + h*SPAN + cl) = o;
            }
          }
    }
}

// link prediction
__global__ __launch_bounds__(128) void k_linkpred(const float* z0,
      const int* src,const int* dst,const int* neg,
      const float* Ws,const float* bs,const float* Wd,const float* bd,
      const float* Wo,const float* bo, float* out){
    __shared__ float zs[D], zd[D], zn[D];
    __shared__ float red[4];
    int b = blockIdx.x; int d = threadIdx.x;
    zs[d] = z0[(size_t)src[b]*D + d];
    zd[d] = z0[(size_t)dst[b]*D + d];
    zn[d] = z0[(size_t)neg[b]*D + d];
    __syncthreads();
    float ss=0.f, sdd=0.f, snn=0.f;
    for(int c=0;c<D;++c){
        float w1 = Ws[c*D + d], w2 = Wd[c*D + d];
        ss  += zs[c]*w1; sdd += zd[c]*w2; snn += zn[c]*w2;
    }
    float bb = bs[d] + bd[d];
    float h1 = fmaxf(ss + sdd + bb, 0.f);
    float h2 = fmaxf(ss + snn + bb, 0.f);
    float w = Wo[d];
    float v1 = h1*w, v2 = h2*w;
    #pragma unroll
    for(int off=32; off; off>>=1){ v1 += __shfl_xor(v1,off); v2 += __shfl_xor(v2,off); }
    int wid = d>>6;
    if((d&63)==0){ red[wid*2]=v1; red[wid*2+1]=v2; }
    __syncthreads();
    if(d==0){
        out[b]       = sigmoidf_(red[0]+red[2] + bo[0]);
        out[BSZ + b] = sigmoidf_(red[1]+red[3] + bo[0]);
    }
}

extern "C" void kernel_launch(void* const* d_in, const int* in_sizes, int n_in,
                              void* d_out, int out_size, void* d_ws, size_t ws_size,
                              hipStream_t stream) {
    const float* memory  = (const float*)d_in[0];
    const float* time_w  = (const float*)d_in[1];
    const float* time_b  = (const float*)d_in[2];
    const float* gWih    = (const float*)d_in[3];
    const float* gbih    = (const float*)d_in[4];
    const float* gWhh    = (const float*)d_in[5];
    const float* gbhh    = (const float*)d_in[6];
    const float* Wq0=(const float*)d_in[7],  *bq0=(const float*)d_in[8];
    const float* Wk0=(const float*)d_in[9],  *bk0=(const float*)d_in[10];
    const float* Wv0=(const float*)d_in[11], *bv0=(const float*)d_in[12];
    const float* Wo0=(const float*)d_in[13], *bo0=(const float*)d_in[14];
    const float* Wq1=(const float*)d_in[15], *bq1=(const float*)d_in[16];
    const float* Wk1=(const float*)d_in[17], *bk1=(const float*)d_in[18];
    const float* Wv1=(const float*)d_in[19], *bv1=(const float*)d_in[20];
    const float* Wo1=(const float*)d_in[21], *bo1=(const float*)d_in[22];
    const float* lpWs=(const float*)d_in[23], *lpbs=(const float*)d_in[24];
    const float* lpWd=(const float*)d_in[25], *lpbd=(const float*)d_in[26];
    const float* lpWo=(const float*)d_in[27], *lpbo=(const float*)d_in[28];
    const float* msgs    = (const float*)d_in[29];
    const float* times0  = (const float*)d_in[30];
    const float* ntimes0 = (const float*)d_in[31];
    const float* nfeats0 = (const float*)d_in[32];
    const float* times1  = (const float*)d_in[33];
    const float* ntimes1 = (const float*)d_in[34];
    const float* nfeats1 = (const float*)d_in[35];
    const int* msg_nids  = (const int*)d_in[36];
    const int* seed0     = (const int*)d_in[37];
    const int* seed1     = (const int*)d_in[38];
    const int* nbr_local0= (const int*)d_in[39];
    const int* nbr_mask0 = (const int*)d_in[40];
    const int* nbr_mask1 = (const int*)d_in[41];
    const int* src       = (const int*)d_in[42];
    const int* dst       = (const int*)d_in[43];
    const int* neg       = (const int*)d_in[44];

    char* ws = (char*)d_ws;
    size_t off = 0;
    auto alloc = [&](size_t bytes)->char*{
        char* p = ws + off;
        off += (bytes + 255) & ~(size_t)255;
        return p;
    };
    int*   map   = (int*)  alloc((size_t)NNC*4);
    float* upd   = (float*)alloc((size_t)MC*D*4);
    unsigned short* hb1   = (unsigned short*)alloc((size_t)N1C*D*2);
    unsigned short* qwb1  = (unsigned short*)alloc((size_t)N1C*464*2);
    unsigned short* acat1 = (unsigned short*)alloc((size_t)N1C*584*2);
    unsigned short* zb1   = (unsigned short*)alloc((size_t)N1C*D*2);
    unsigned short* hb0   = (unsigned short*)alloc((size_t)N0C*D*2);
    unsigned short* qwb0  = (unsigned short*)alloc((size_t)N0C*720*2);
    unsigned short* acat0 = (unsigned short*)alloc((size_t)N0C*840*2);
    float* z0    = (float*)alloc((size_t)N0C*D*4);
    float* qc0   = (float*)alloc(512);
    float* qc1   = (float*)alloc(512);
    float* cb0   = (float*)alloc(512);
    float* cb1   = (float*)alloc(512);
    unsigned short* WFb0 = (unsigned short*)alloc((size_t)D*720*2);
    unsigned short* WFb1 = (unsigned short*)alloc((size_t)D*464*2);
    float* cF0   = (float*)alloc((size_t)720*4);
    float* cF1   = (float*)alloc((size_t)464*4);
    unsigned short* Bcat1 = (unsigned short*)alloc((size_t)584*D*2);
    unsigned short* Bcat0 = (unsigned short*)alloc((size_t)840*D*2);
    unsigned short* gA    = (unsigned short*)alloc((size_t)MC*GKP*2);
    unsigned short* gB    = (unsigned short*)alloc((size_t)GK*GN*2);
    float* gBias = (float*)alloc((size_t)GN*4);
    float* hprevf= (float*)alloc((size_t)MC*D*4);
    float* part  = (float*)alloc((size_t)2*N1C*D*4);   // 31.5 MB, GRU split3 (25.2MB) + hop0 split4 (12.6MB) fit
    float* outp = (float*)d_out;

    // precompute (gru bias fused in)
    k_pre_small<<<1,512,0,stream>>>(time_b, Wq0,bq0,Wq1,bq1, bv0,Wo0,bo0, bv1,Wo1,bo1,
                                    gbih, gbhh, gBias, qc0,qc1,cb0,cb1);
    k_wf<<<720,128,0,stream>>>(Wq0,Wk0,bk0,qc0, WFb0,cF0, 0);
    k_wf<<<464,128,0,stream>>>(Wq1,Wk1,bk1,qc1, WFb1,cF1, 128);
    k_bcat<<<584,128,0,stream>>>(Wv1, Wo1, Bcat1, 128);
    k_bcat<<<840,128,0,stream>>>(Wv0, Wo0, Bcat0, 0);
    k_gruB<<<dim3(10,8),256,0,stream>>>(gWih, gWhh, gB);

    // GRU memory update via split-K MFMA GEMM + fused reduce/gates (map scatter fused in acvt)
    k_acvt<<<(MC*GKP+255)/256,256,0,stream>>>(msgs, memory, msg_nids, gA, hprevf, map);
    k_gmm<128,3,false,true><<<dim3(GN/64, MC/128, 3),256,0,stream>>>(gA,GKP, gB,GN, gBias, part,GN, GK, GN, MC);
    k_gates3<<<(MC*D+255)/256,256,0,stream>>>(part, gBias, hprevf, upd);

    // gather node states (both hops) -> bf16
    k_gatherf<<<((N1C+N0C)*D)/256,256,0,stream>>>(seed1, seed0, map, msg_nids, memory, upd,
                                                  hb1, acat1, hb0, acat0);

    // GEMM1 (MFMA): qw = h @ WF + cF
    k_gmm<128,1,false,false><<<dim3(8,  N1C/128),256,0,stream>>>(hb1,128, WFb1,464, cF1, qwb1,464, 128, 464, N1C);
    k_gmm<128,1,false,false><<<dim3(12, N0C/128),256,0,stream>>>(hb0,128, WFb0,720, cF0, qwb0,720, 128, 720, N0C);

    // hop 1 attention (7680 blocks)
    k_attn<K1C,128,1,1><<<N1C/4,256,0,stream>>>(qwb1, acat1, 584, times1, ntimes1, nfeats1,
                                                nbr_mask1, (const int*)0, (const unsigned short*)0,
                                                time_w, time_b);
    // GEMM2 hop1: single-pass fused bias+relu -> bf16 zb1 (480 blocks; removes 63MB
    // split-K partial traffic + the k_kred launch)
    k_gmm<128,1,true,false><<<dim3(2, N1C/128),256,0,stream>>>(acat1,584, Bcat1,D, cb1, zb1,D, 584, D, N1C);

    // hop 0 attention (1536 blocks)
    k_attn<K0C,0,2,1><<<N0C/4,256,0,stream>>>(qwb0, acat0, 840, times0, ntimes0, nfeats0,
                                              nbr_mask0, nbr_local0, zb1,
                                              time_w, time_b);
    // GEMM2 hop0: BM=64, split-K=4 (768 blocks) + reduce -> f32 z0
    k_gmm<64,4,true,true><<<dim3(2, N0C/64, 4),256,0,stream>>>(acat0,840, Bcat0,D, cb0, part,D, 840, D, N0C);
    k_kred<4,true,true><<<(N0C*D+255)/256,256,0,stream>>>(part, N0C, D, cb0, z0);

    // link prediction
    k_linkpred<<<BSZ,128,0,stream>>>(z0, src,dst,neg, lpWs,lpbs,lpWd,lpbd, lpWo,lpbo, outp);
}

// Round 12
// 517.155 us; speedup vs baseline: 1.1427x; 1.0517x over previous
//
#include <hip/hip_runtime.h>
#include <math.h>

// ---- problem constants ----
#define D    128
#define TT   128
#define E    100
#define NHD  2
#define BSZ  2048
#define N0C  6144
#define K0C  5
#define N1C  30720
#define K1C  10
#define NNC  200000
#define MC   4096
#define MSG  484
#define KIN  356        // D+E+T
#define GK   612        // MSG + D (GRU GEMM K)
#define GKP  616        // padded to 8
#define GN   512        // GRU GEMM N (256 rz-sum + 128 in + 128 hn)

// WF geometry
#define HSTR0 360
#define WID0  720
#define SPAN0 356
#define HSTR1 232
#define WID1  464
#define SPAN1 228

// mega-kernel block routing
#define WF0_BASE   1
#define WF0_BLKS   360
#define WF1_BASE   (WF0_BASE+WF0_BLKS)      // 361
#define WF1_BLKS   232
#define BC1_BASE   (WF1_BASE+WF1_BLKS)      // 593
#define BC1_BLKS   292
#define BC0_BASE   (BC1_BASE+BC1_BLKS)      // 885
#define BC0_BLKS   420
#define GRUB_BASE  (BC0_BASE+BC0_BLKS)      // 1305
#define GRUB_BLKS  80
#define ACVT_BASE  (GRUB_BASE+GRUB_BLKS)    // 1385
#define ACVT_BLKS  ((MC*GKP)/256)           // 9856
#define MEGA_BLKS  (ACVT_BASE+ACVT_BLKS)    // 11241

typedef __attribute__((ext_vector_type(8))) short short8v;   // 8 bf16 (4 VGPRs)
typedef __attribute__((ext_vector_type(4))) float f32x4;

__device__ __forceinline__ float sigmoidf_(float x){ return 1.f/(1.f+__expf(-x)); }
__device__ __forceinline__ unsigned short f2b(float f){
    unsigned int x = __float_as_uint(f);
    unsigned int r = (x + 0x7fffu + ((x>>16)&1u)) >> 16;
    return (unsigned short)r;
}
__device__ __forceinline__ float b2f(unsigned short u){
    return __uint_as_float(((unsigned int)u)<<16);
}

// ---------- MEGA: all input-only precompute fused into one dispatch ----------
// block 0        : smalls — cosb->qc (LDS), cF0/cF1, cb0/cb1, gBias
// [WF0..)        : WF0 (2 idx / block)      [WF1..): WF1
// [BC1..)        : Bcat1 (2 r / block)      [BC0..): Bcat0
// [GRUB..)       : gruB LDS-transpose       [ACVT..): gA convert + map scatter
// No cross-block deps: the qc->cF chain lives entirely inside block 0.
__global__ __launch_bounds__(256) void k_mega(
    const float* __restrict__ time_b,
    const float* __restrict__ Wq0,const float* __restrict__ bq0,
    const float* __restrict__ Wk0,const float* __restrict__ bk0,
    const float* __restrict__ Wq1,const float* __restrict__ bq1,
    const float* __restrict__ Wk1,const float* __restrict__ bk1,
    const float* __restrict__ Wv0,const float* __restrict__ Wo0,
    const float* __restrict__ bv0,const float* __restrict__ bo0,
    const float* __restrict__ Wv1,const float* __restrict__ Wo1,
    const float* __restrict__ bv1,const float* __restrict__ bo1,
    const float* __restrict__ gWih,const float* __restrict__ gWhh,
    const float* __restrict__ gbih,const float* __restrict__ gbhh,
    const float* __restrict__ msgs,const float* __restrict__ memory,
    const int* __restrict__ msg_nids,
    unsigned short* __restrict__ WF0, float* __restrict__ cF0,
    unsigned short* __restrict__ WF1, float* __restrict__ cF1,
    unsigned short* __restrict__ Bcat0, unsigned short* __restrict__ Bcat1,
    unsigned short* __restrict__ gB, float* __restrict__ gBias,
    float* __restrict__ cb0, float* __restrict__ cb1,
    unsigned short* __restrict__ gA, float* __restrict__ hprevf,
    int* __restrict__ map)
{
    __shared__ float smem[64*65];
    int b = blockIdx.x;
    int t = threadIdx.x;

    if(b >= ACVT_BASE){
        // ---- acvt: A-matrix bf16 convert + hprev stash + map scatter ----
        int i = (b-ACVT_BASE)*256 + t;
        if(i >= MC*GKP) return;
        int row = i / GKP; int c = i - row*GKP;
        if(c == 0) map[msg_nids[row]] = row;
        float v;
        if(c < MSG) v = msgs[(size_t)row*MSG + c];
        else if(c < GK){ int d = c-MSG; v = memory[(size_t)msg_nids[row]*D + d]; hprevf[row*D+d] = v; }
        else v = 0.f;
        gA[i] = f2b(v);
        return;
    }
    if(b >= GRUB_BASE){
        // ---- gruB: packed GRU B (612x512 bf16) via LDS transpose ----
        int i = b - GRUB_BASE;
        int rb = (i%10)*64, jb = (i/10)*64;
        float (*tile)[65] = (float(*)[65])smem;
        int rr = t&63, jj0 = t>>6;
        #pragma unroll
        for(int q=0;q<16;++q){
            int jj = jj0 + q*4;
            int j = jb + jj; int r = rb + rr;
            float v = 0.f;
            if(r < GK){
                if(j < 256)      v = (r<MSG)? gWih[(size_t)j*MSG+r] : gWhh[(size_t)j*D + (r-MSG)];
                else if(j < 384) v = (r<MSG)? gWih[(size_t)j*MSG+r] : 0.f;
                else             v = (r<MSG)? 0.f : gWhh[(size_t)(j-128)*D + (r-MSG)];
            }
            tile[jj][rr] = v;
        }
        __syncthreads();
        int jw = t&63, rr0 = t>>6;
        #pragma unroll
        for(int q=0;q<16;++q){
            int rr2 = rr0 + q*4;
            int r = rb + rr2;
            if(r < GK) gB[(size_t)r*GN + jb + jw] = f2b(tile[jw][rr2]);
        }
        return;
    }
    if(b >= BC0_BASE){
        // ---- Bcat0 (cmin=0, span=356, rows=712, range 840) ----
        int g = t>>7, j = t&127;
        int r = (b - BC0_BASE)*2 + g;
        float a;
        if(r < 712){
            int h = r/356; int c = r - h*356;
            a = 0.f;
            for(int d=0; d<64; ++d) a += Wv0[c*D + h*64+d] * Wo0[(h*64+d)*D + j];
        } else {
            a = Wo0[(size_t)(D + (r - 712))*D + j];
        }
        Bcat0[(size_t)r*D + j] = f2b(a);
        return;
    }
    if(b >= BC1_BASE){
        // ---- Bcat1 (cmin=128, span=228, rows=456, range 584) ----
        int g = t>>7, j = t&127;
        int r = (b - BC1_BASE)*2 + g;
        float a;
        if(r < 456){
            int h = r/228; int c = 128 + (r - h*228);
            a = 0.f;
            for(int d=0; d<64; ++d) a += Wv1[c*D + h*64+d] * Wo1[(h*64+d)*D + j];
        } else {
            a = Wo1[(size_t)(D + (r - 456))*D + j];
        }
        Bcat1[(size_t)r*D + j] = f2b(a);
        return;
    }
    if(b >= WF1_BASE){
        // ---- WF1 (cmin=128) ----
        int g = t>>7, k = t&127;
        int idx = (b - WF1_BASE)*2 + g;
        int h = idx/HSTR1, cl = idx - h*HSTR1;
        if(cl > SPAN1){ WF1[(size_t)k*WID1 + idx] = (unsigned short)0; return; }
        int c = 128 + cl;
        float a = 0.f;
        for(int d=0; d<64; ++d){
            float wkv = (c < KIN) ? Wk1[c*D + h*64+d] : bk1[h*64+d];
            a += Wq1[k*D + h*64+d] * wkv;
        }
        WF1[(size_t)k*WID1 + idx] = f2b(a);
        return;
    }
    if(b >= WF0_BASE){
        // ---- WF0 (cmin=0) ----
        int g = t>>7, k = t&127;
        int idx = (b - WF0_BASE)*2 + g;
        int h = idx/HSTR0, cl = idx - h*HSTR0;
        if(cl > SPAN0){ WF0[(size_t)k*WID0 + idx] = (unsigned short)0; return; }
        int c = cl;
        float a = 0.f;
        for(int d=0; d<64; ++d){
            float wkv = (c < KIN) ? Wk0[c*D + h*64+d] : bk0[h*64+d];
            a += Wq0[k*D + h*64+d] * wkv;
        }
        WF0[(size_t)k*WID0 + idx] = f2b(a);
        return;
    }

    // ---- block 0: smalls ----
    // cosb -> smem[0..128)
    if(t < 128) smem[t] = cosf(time_b[t]);
    __syncthreads();
    // qc0 -> smem[128..256), qc1 -> smem[256..384)
    if(t < 128){
        float a0 = bq0[t], a1 = bq1[t];
        for(int tt=0; tt<TT; ++tt){
            float cb = smem[tt];
            a0 += cb*Wq0[(D+tt)*D + t];
            a1 += cb*Wq1[(D+tt)*D + t];
        }
        smem[128+t] = a0; smem[256+t] = a1;
    }
    // cb0 / cb1 (no qc dep)
    {
        int j = t&127;
        const float* bo = (t<128)? bo0 : bo1;
        const float* bv = (t<128)? bv0 : bv1;
        const float* Wo = (t<128)? Wo0 : Wo1;
        float c = bo[j];
        for(int jp=0; jp<D; ++jp) c += bv[jp]*Wo[jp*D + j];
        if(t<128) cb0[j] = c; else cb1[j] = c;
    }
    // gBias
    for(int j=t; j<GN; j+=256){
        float v;
        if(j < 256)      v = gbih[j] + gbhh[j];
        else if(j < 384) v = gbih[j];
        else             v = gbhh[j-128];
        gBias[j] = v;
    }
    __syncthreads();
    // cF0 (720) + cF1 (464): 1184 entries, 5 strided iters
    for(int q=0; q<5; ++q){
        int gi = t + q*256;
        if(gi < WID0){
            int idx = gi; int h = idx/HSTR0, cl = idx - h*HSTR0;
            float s = 0.f;
            if(cl <= SPAN0){
                int c = cl;
                for(int d=0; d<64; ++d){
                    float wkv = (c < KIN) ? Wk0[c*D + h*64+d] : bk0[h*64+d];
                    s += smem[128 + h*64+d]*wkv;
                }
            }
            cF0[idx] = s;
        } else if(gi < WID0+WID1){
            int idx = gi - WID0; int h = idx/HSTR1, cl = idx - h*HSTR1;
            float s = 0.f;
            if(cl <= SPAN1){
                int c = 128 + cl;
                for(int d=0; d<64; ++d){
                    float wkv = (c < KIN) ? Wk1[c*D + h*64+d] : bk1[h*64+d];
                    s += smem[256 + h*64+d]*wkv;
                }
            }
            cF1[idx] = s;
        }
    }
}

// fused split-K reduce + gates: upd = (1-u)*tanh(inn + r*hn) + u*h
__global__ void k_gates3(const float* part, const float* bias, const float* hprevf, float* upd){
    int i = blockIdx.x*256 + threadIdx.x;
    if(i >= MC*D) return;
    int row = i>>7, d = i&127;
    const float* p = part + (size_t)row*GN;
    const size_t S = (size_t)MC*GN;
    float gr = p[d]     + p[S+d]     + p[2*S+d]     + bias[d];
    float gu = p[128+d] + p[S+128+d] + p[2*S+128+d] + bias[128+d];
    float gi = p[256+d] + p[S+256+d] + p[2*S+256+d] + bias[256+d];
    float gh = p[384+d] + p[S+384+d] + p[2*S+384+d] + bias[384+d];
    float r = sigmoidf_(gr);
    float u = sigmoidf_(gu);
    float n = tanhf(gi + r*gh);
    upd[i] = (1.f-u)*n + u*hprevf[i];
}

// fused gather for both hops; map entry valid iff msg_nids[mi]==sid (no map init required)
__global__ void k_gatherf(const int* seed1,const int* seed0,const int* map,const int* msg_nids,
                          const float* memory,const float* upd,
                          unsigned short* hb1, unsigned short* acat1,
                          unsigned short* hb0, unsigned short* acat0){
    int i = blockIdx.x*256 + threadIdx.x;
    const int total1 = N1C*D;
    int li; const int* seed; unsigned short* hb; unsigned short* acat; int ldav, hoff;
    if(i < total1){ li=i; seed=seed1; hb=hb1; acat=acat1; ldav=584; hoff=456; }
    else { li = i - total1; if(li >= N0C*D) return; seed=seed0; hb=hb0; acat=acat0; ldav=840; hoff=712; }
    int row = li>>7, c = li&127;
    int sid = seed[row];
    int mi = map[sid];
    bool valid = ((unsigned)mi < (unsigned)MC) && (msg_nids[mi] == sid);
    float v = valid ? upd[(size_t)mi*D + c] : memory[(size_t)sid*D + c];
    unsigned short u = f2b(v);
    hb[li] = u;
    acat[(size_t)row*ldav + hoff + c] = u;
}

// ---------- bf16 MFMA GEMM, reg-prefetch pipelined, optional split-K ----------
// SPLITK>1: writes f32 partials [z][M][ldc], no bias/relu
template<int BM, int SPLITK, bool RELU, bool OUTF32>
__global__ __launch_bounds__(256) void k_gmm(const unsigned short* A, int lda,
                                             const unsigned short* B, int ldb,
                                             const float* bias, void* Cp, int ldc,
                                             int K, int N, int M){
    constexpr int ASTR = 72;
    constexpr int BSTR = 72;
    constexpr int RPW = BM/4;
    constexpr int RT  = RPW/16;
    constexpr int AIT = BM/32;
    __shared__ unsigned short As[BM*ASTR];
    __shared__ unsigned short Bs[64*BSTR];
    int t = threadIdx.x;
    int wave = t>>6, lane = t&63;
    int l15 = lane&15, l4 = lane>>4;
    int m0 = blockIdx.y*BM, n0 = blockIdx.x*64;
    int ntiles = (K+63)>>6;
    int tbeg, tend;
    if(SPLITK==1){ tbeg=0; tend=ntiles; }
    else {
        int tper = (ntiles + SPLITK-1)/SPLITK;
        tbeg = blockIdx.z*tper;
        tend = min(ntiles, tbeg+tper);
    }
    f32x4 acc[RT][4];
    #pragma unroll
    for(int rt=0;rt<RT;++rt)
        #pragma unroll
        for(int ct=0;ct<4;++ct) acc[rt][ct] = (f32x4){0.f,0.f,0.f,0.f};

    uint4 apre[AIT]; unsigned short bpre[16];
    auto loadA = [&](int kt){
        int k0 = kt<<6;
        #pragma unroll
        for(int i=0;i<AIT;++i){
            int idx = t + i*256;
            int row = idx>>3; int kc = (idx&7)*8;
            uint4 v = {0u,0u,0u,0u};
            if(k0+kc < K) v = *(const uint4*)(A + (size_t)(m0+row)*lda + k0 + kc);
            apre[i] = v;
        }
    };
    auto loadB = [&](int kt){
        int k0 = kt<<6;
        int n = t&63; int kb = (t>>6)*16;
        int ng = n0+n;
        #pragma unroll
        for(int j=0;j<16;++j){
            int kg = k0 + kb + j;
            bpre[j] = (kg<K && ng<N) ? B[(size_t)kg*ldb + ng] : (unsigned short)0;
        }
    };
    auto stash = [&](){
        #pragma unroll
        for(int i=0;i<AIT;++i){
            int idx = t + i*256;
            int row = idx>>3; int kc = (idx&7)*8;
            *(uint4*)&As[row*ASTR + kc] = apre[i];
        }
        int n = t&63; int kb = (t>>6)*16;
        #pragma unroll
        for(int j=0;j<16;++j) Bs[n*BSTR + kb + j] = bpre[j];
    };

    loadA(tbeg); loadB(tbeg);
    for(int kt=tbeg; kt<tend; ++kt){
        stash();
        __syncthreads();
        if(kt+1 < tend){ loadA(kt+1); loadB(kt+1); }
        #pragma unroll
        for(int kk=0; kk<64; kk+=32){
            short8v bfr[4];
            #pragma unroll
            for(int ct=0;ct<4;++ct)
                bfr[ct] = *(const short8v*)&Bs[(ct*16+l15)*BSTR + kk + l4*8];
            #pragma unroll
            for(int rt=0;rt<RT;++rt){
                short8v afr = *(const short8v*)&As[(wave*RPW + rt*16 + l15)*ASTR + kk + l4*8];
                #pragma unroll
                for(int ct=0;ct<4;++ct)
                    acc[rt][ct] = __builtin_amdgcn_mfma_f32_16x16x32_bf16(afr, bfr[ct], acc[rt][ct], 0,0,0);
            }
        }
        __syncthreads();
    }
    #pragma unroll
    for(int rt=0;rt<RT;++rt){
        #pragma unroll
        for(int ct=0;ct<4;++ct){
            int col = n0 + ct*16 + l15;
            if(col < N){
                #pragma unroll
                for(int r=0;r<4;++r){
                    int row = m0 + wave*RPW + rt*16 + l4*4 + r;
                    if(SPLITK==1){
                        float v = acc[rt][ct][r] + bias[col];
                        if(RELU) v = fmaxf(v, 0.f);
                        if(OUTF32) ((float*)Cp)[(size_t)row*ldc + col] = v;
                        else ((unsigned short*)Cp)[(size_t)row*ldc + col] = f2b(v);
                    } else {
                        ((float*)Cp)[((size_t)blockIdx.z*M + row)*ldc + col] = acc[rt][ct][r];
                    }
                }
            }
        }
    }
}

// split-K reduce + bias (+relu); N power of two
template<int SPL, bool RELU, bool OUTF32>
__global__ void k_kred(const float* part, int M, int N, const float* bias, void* out){
    int i = blockIdx.x*256 + threadIdx.x;
    if(i >= M*N) return;
    int col = i & (N-1);
    float v = bias[col];
    #pragma unroll
    for(int z=0;z<SPL;++z) v += part[(size_t)z*M*N + i];
    if(RELU) v = fmaxf(v, 0.f);
    if(OUTF32) ((float*)out)[i] = v;
    else ((unsigned short*)out)[i] = f2b(v);
}

// fused scores + masked softmax + av — EXACT Round-2 structure (measured 75 us attn1).
// Alternatives measured worse: LDS staging (101 us, R4), asm-pinned regs (105 us, R9).
// The compiler's remat-for-occupancy tradeoff (VGPR=44) is the measured optimum.
template<int K, int CMIN, int S4, int NPW>
__global__ __launch_bounds__(256) void k_attn(const unsigned short* __restrict__ qwb,
    unsigned short* __restrict__ avout, int ldav,
    const float* __restrict__ times, const float* __restrict__ nbr_times,
    const float* __restrict__ nbr_feats,
    const int* __restrict__ nbr_mask, const int* __restrict__ nbr_local,
    const unsigned short* __restrict__ zbuf,
    const float* __restrict__ time_w, const float* __restrict__ time_b){
    constexpr int SPAN = KIN - CMIN;
    constexpr int QSTR = SPAN + 4;
    constexpr int QLD  = 2*QSTR;
    int wv = __builtin_amdgcn_readfirstlane(blockIdx.x*4 + (threadIdx.x>>6));
    int lane = threadIdx.x & 63;

    float4 tw4[S4], tb4[S4];
    #pragma unroll
    for(int s=0;s<S4;++s){
        int c = CMIN + s*256 + lane*4;
        if(c >= D+E && c < KIN){
            tw4[s] = *(const float4*)(time_w + (c-(D+E)));
            tb4[s] = *(const float4*)(time_b + (c-(D+E)));
        } else {
            tw4[s] = make_float4(0.f,0.f,0.f,0.f);
            tb4[s] = make_float4(0.f,0.f,0.f,0.f);
        }
    }

    #pragma unroll
    for(int i=0;i<NPW;++i){
        int n = wv*NPW + i;
        const unsigned short* qrow = qwb + (size_t)n*QLD;
        float tn = times[n];
        int   mk[K]; float tk[K]; int nl[K];
        #pragma unroll
        for(int k=0;k<K;++k){
            mk[k] = nbr_mask [(size_t)n*K + k];
            tk[k] = nbr_times[(size_t)n*K + k];
            nl[k] = (CMIN==0) ? nbr_local[(size_t)n*K + k] : 0;
        }

        float4 qw4[NHD][S4]; float qb[NHD];
        #pragma unroll
        for(int h=0;h<NHD;++h){
            qb[h] = b2f(qrow[h*QSTR + SPAN]);
            #pragma unroll
            for(int s=0;s<S4;++s){
                int cl = s*256 + lane*4;
                float4 v = make_float4(0.f,0.f,0.f,0.f);
                if(cl < SPAN){
                    uint2 wq = *(const uint2*)(qrow + h*QSTR + cl);
                    v.x = __uint_as_float(wq.x<<16);
                    v.y = __uint_as_float(wq.x & 0xffff0000u);
                    v.z = __uint_as_float(wq.y<<16);
                    v.w = __uint_as_float(wq.y & 0xffff0000u);
                }
                qw4[h][s] = v;
            }
        }

        // phase 1: materialize kin for ALL neighbors (loads batched, no branches over k)
        float4 kin4[K][S4];
        #pragma unroll
        for(int k=0;k<K;++k){
            float dt = tn - tk[k];
            const float* ef = nbr_feats + (size_t)(n*K+k)*E;
            const unsigned short* zf = (CMIN==0) ?
                (zbuf + (size_t)(nl[k] - N0C)*D) : (const unsigned short*)0;
            #pragma unroll
            for(int s=0;s<S4;++s){
                int c = CMIN + s*256 + lane*4;
                float4 kv = make_float4(0.f,0.f,0.f,0.f);
                if(c < KIN){
                    if(CMIN==0 && c < D){
                        uint2 wz = *(const uint2*)(zf + c);
                        kv.x = __uint_as_float(wz.x<<16);
                        kv.y = __uint_as_float(wz.x & 0xffff0000u);
                        kv.z = __uint_as_float(wz.y<<16);
                        kv.w = __uint_as_float(wz.y & 0xffff0000u);
                    } else if(c < D+E){
                        kv = *(const float4*)(ef + (c-D));
                    } else {
                        kv.x = __cosf(dt*tw4[s].x + tb4[s].x);
                        kv.y = __cosf(dt*tw4[s].y + tb4[s].y);
                        kv.z = __cosf(dt*tw4[s].z + tb4[s].z);
                        kv.w = __cosf(dt*tw4[s].w + tb4[s].w);
                    }
                }
                kin4[k][s] = kv;
            }
        }

        // phase 2: lane-partial dot products for all (head, k)
        float p0[K], p1[K];
        #pragma unroll
        for(int k=0;k<K;++k){
            float a0 = 0.f, a1 = 0.f;
            #pragma unroll
            for(int s=0;s<S4;++s){
                float4 kv = kin4[k][s];
                a0 += kv.x*qw4[0][s].x + kv.y*qw4[0][s].y + kv.z*qw4[0][s].z + kv.w*qw4[0][s].w;
                a1 += kv.x*qw4[1][s].x + kv.y*qw4[1][s].y + kv.z*qw4[1][s].z + kv.w*qw4[1][s].w;
            }
            p0[k] = a0; p1[k] = a1;
        }

        // phase 3: one interleaved butterfly — 2K independent chains per step
        #pragma unroll
        for(int off=32; off; off>>=1){
            #pragma unroll
            for(int k=0;k<K;++k){
                p0[k] += __shfl_xor(p0[k], off);
                p1[k] += __shfl_xor(p1[k], off);
            }
        }

        float sval[NHD][K];
        #pragma unroll
        for(int k=0;k<K;++k){
            bool act = mk[k] > 0;
            sval[0][k] = act ? (p0[k] + qb[0])*0.125f : -1e9f;
            sval[1][k] = act ? (p1[k] + qb[1])*0.125f : -1e9f;
        }
        #pragma unroll
        for(int h=0;h<NHD;++h){
            float mx = -1e30f;
            #pragma unroll
            for(int k=0;k<K;++k) mx = fmaxf(mx, sval[h][k]);
            float z=0.f;
            #pragma unroll
            for(int k=0;k<K;++k){ float e = __expf(sval[h][k]-mx); sval[h][k]=e; z+=e; }
            float inv = 1.f/z;
            #pragma unroll
            for(int k=0;k<K;++k) sval[h][k]*=inv;
        }
        // AV: unconditional — masked weights are exactly 0
        #pragma unroll
        for(int h=0;h<NHD;++h)
          #pragma unroll
          for(int s=0;s<S4;++s){
            int cl = s*256 + lane*4;
            if(cl < SPAN){
                float v0=0.f,v1=0.f,v2=0.f,v3=0.f;
                #pragma unroll
                for(int k=0;k<K;++k){
                    float a = sval[h][k];
                    v0 += a*kin4[k][s].x; v1 += a*kin4[k][s].y;
                    v2 += a*kin4[k][s].z; v3 += a*kin4[k][s].w;
                }
                uint2 o;
                o.x = (unsigned int)f2b(v0) | ((unsigned int)f2b(v1)<<16);
                o.y = (unsigned int)f2b(v2) | ((unsigned int)f2b(v3)<<16);
                *(uint2*)(avout + (size_t)n*ldav + h*SPAN + cl) = o;
            }
          }
    }
}

// link prediction
__global__ __launch_bounds__(128) void k_linkpred(const float* z0,
      const int* src,const int* dst,const int* neg,
      const float* Ws,const float* bs,const float* Wd,const float* bd,
      const float* Wo,const float* bo, float* out){
    __shared__ float zs[D], zd[D], zn[D];
    __shared__ float red[4];
    int b = blockIdx.x; int d = threadIdx.x;
    zs[d] = z0[(size_t)src[b]*D + d];
    zd[d] = z0[(size_t)dst[b]*D + d];
    zn[d] = z0[(size_t)neg[b]*D + d];
    __syncthreads();
    float ss=0.f, sdd=0.f, snn=0.f;
    for(int c=0;c<D;++c){
        float w1 = Ws[c*D + d], w2 = Wd[c*D + d];
        ss  += zs[c]*w1; sdd += zd[c]*w2; snn += zn[c]*w2;
    }
    float bb = bs[d] + bd[d];
    float h1 = fmaxf(ss + sdd + bb, 0.f);
    float h2 = fmaxf(ss + snn + bb, 0.f);
    float w = Wo[d];
    float v1 = h1*w, v2 = h2*w;
    #pragma unroll
    for(int off=32; off; off>>=1){ v1 += __shfl_xor(v1,off); v2 += __shfl_xor(v2,off); }
    int wid = d>>6;
    if((d&63)==0){ red[wid*2]=v1; red[wid*2+1]=v2; }
    __syncthreads();
    if(d==0){
        out[b]       = sigmoidf_(red[0]+red[2] + bo[0]);
        out[BSZ + b] = sigmoidf_(red[1]+red[3] + bo[0]);
    }
}

extern "C" void kernel_launch(void* const* d_in, const int* in_sizes, int n_in,
                              void* d_out, int out_size, void* d_ws, size_t ws_size,
                              hipStream_t stream) {
    const float* memory  = (const float*)d_in[0];
    const float* time_w  = (const float*)d_in[1];
    const float* time_b  = (const float*)d_in[2];
    const float* gWih    = (const float*)d_in[3];
    const float* gbih    = (const float*)d_in[4];
    const float* gWhh    = (const float*)d_in[5];
    const float* gbhh    = (const float*)d_in[6];
    const float* Wq0=(const float*)d_in[7],  *bq0=(const float*)d_in[8];
    const float* Wk0=(const float*)d_in[9],  *bk0=(const float*)d_in[10];
    const float* Wv0=(const float*)d_in[11], *bv0=(const float*)d_in[12];
    const float* Wo0=(const float*)d_in[13], *bo0=(const float*)d_in[14];
    const float* Wq1=(const float*)d_in[15], *bq1=(const float*)d_in[16];
    const float* Wk1=(const float*)d_in[17], *bk1=(const float*)d_in[18];
    const float* Wv1=(const float*)d_in[19], *bv1=(const float*)d_in[20];
    const float* Wo1=(const float*)d_in[21], *bo1=(const float*)d_in[22];
    const float* lpWs=(const float*)d_in[23], *lpbs=(const float*)d_in[24];
    const float* lpWd=(const float*)d_in[25], *lpbd=(const float*)d_in[26];
    const float* lpWo=(const float*)d_in[27], *lpbo=(const float*)d_in[28];
    const float* msgs    = (const float*)d_in[29];
    const float* times0  = (const float*)d_in[30];
    const float* ntimes0 = (const float*)d_in[31];
    const float* nfeats0 = (const float*)d_in[32];
    const float* times1  = (const float*)d_in[33];
    const float* ntimes1 = (const float*)d_in[34];
    const float* nfeats1 = (const float*)d_in[35];
    const int* msg_nids  = (const int*)d_in[36];
    const int* seed0     = (const int*)d_in[37];
    const int* seed1     = (const int*)d_in[38];
    const int* nbr_local0= (const int*)d_in[39];
    const int* nbr_mask0 = (const int*)d_in[40];
    const int* nbr_mask1 = (const int*)d_in[41];
    const int* src       = (const int*)d_in[42];
    const int* dst       = (const int*)d_in[43];
    const int* neg       = (const int*)d_in[44];

    char* ws = (char*)d_ws;
    size_t off = 0;
    auto alloc = [&](size_t bytes)->char*{
        char* p = ws + off;
        off += (bytes + 255) & ~(size_t)255;
        return p;
    };
    int*   map   = (int*)  alloc((size_t)NNC*4);
    float* upd   = (float*)alloc((size_t)MC*D*4);
    unsigned short* hb1   = (unsigned short*)alloc((size_t)N1C*D*2);
    unsigned short* qwb1  = (unsigned short*)alloc((size_t)N1C*464*2);
    unsigned short* acat1 = (unsigned short*)alloc((size_t)N1C*584*2);
    unsigned short* zb1   = (unsigned short*)alloc((size_t)N1C*D*2);
    unsigned short* hb0   = (unsigned short*)alloc((size_t)N0C*D*2);
    unsigned short* qwb0  = (unsigned short*)alloc((size_t)N0C*720*2);
    unsigned short* acat0 = (unsigned short*)alloc((size_t)N0C*840*2);
    float* z0    = (float*)alloc((size_t)N0C*D*4);
    float* cb0   = (float*)alloc(512);
    float* cb1   = (float*)alloc(512);
    unsigned short* WFb0 = (unsigned short*)alloc((size_t)D*720*2);
    unsigned short* WFb1 = (unsigned short*)alloc((size_t)D*464*2);
    float* cF0   = (float*)alloc((size_t)720*4);
    float* cF1   = (float*)alloc((size_t)464*4);
    unsigned short* Bcat1 = (unsigned short*)alloc((size_t)584*D*2);
    unsigned short* Bcat0 = (unsigned short*)alloc((size_t)840*D*2);
    unsigned short* gA    = (unsigned short*)alloc((size_t)MC*GKP*2);
    unsigned short* gB    = (unsigned short*)alloc((size_t)GK*GN*2);
    float* gBias = (float*)alloc((size_t)GN*4);
    float* hprevf= (float*)alloc((size_t)MC*D*4);
    float* part  = (float*)alloc((size_t)2*N1C*D*4);   // 31.5 MB, GRU split3 (25.2MB) + hop0 split4 (12.6MB) fit
    float* outp = (float*)d_out;

    // ALL input-only precompute in one dispatch (was 7 launches incl. a 1-block kernel)
    k_mega<<<MEGA_BLKS,256,0,stream>>>(time_b,
        Wq0,bq0,Wk0,bk0, Wq1,bq1,Wk1,bk1,
        Wv0,Wo0,bv0,bo0, Wv1,Wo1,bv1,bo1,
        gWih,gWhh,gbih,gbhh, msgs,memory,msg_nids,
        WFb0,cF0, WFb1,cF1, Bcat0,Bcat1, gB,gBias, cb0,cb1,
        gA,hprevf, map);

    // GRU memory update via split-K MFMA GEMM + fused reduce/gates
    k_gmm<128,3,false,true><<<dim3(GN/64, MC/128, 3),256,0,stream>>>(gA,GKP, gB,GN, gBias, part,GN, GK, GN, MC);
    k_gates3<<<(MC*D+255)/256,256,0,stream>>>(part, gBias, hprevf, upd);

    // gather node states (both hops) -> bf16
    k_gatherf<<<((N1C+N0C)*D)/256,256,0,stream>>>(seed1, seed0, map, msg_nids, memory, upd,
                                                  hb1, acat1, hb0, acat0);

    // GEMM1 (MFMA): qw = h @ WF + cF
    k_gmm<128,1,false,false><<<dim3(8,  N1C/128),256,0,stream>>>(hb1,128, WFb1,464, cF1, qwb1,464, 128, 464, N1C);
    k_gmm<128,1,false,false><<<dim3(12, N0C/128),256,0,stream>>>(hb0,128, WFb0,720, cF0, qwb0,720, 128, 720, N0C);

    // hop 1 attention (7680 blocks)
    k_attn<K1C,128,1,1><<<N1C/4,256,0,stream>>>(qwb1, acat1, 584, times1, ntimes1, nfeats1,
                                                nbr_mask1, (const int*)0, (const unsigned short*)0,
                                                time_w, time_b);
    // GEMM2 hop1: single-pass fused bias+relu -> bf16 zb1 (480 blocks)
    k_gmm<128,1,true,false><<<dim3(2, N1C/128),256,0,stream>>>(acat1,584, Bcat1,D, cb1, zb1,D, 584, D, N1C);

    // hop 0 attention (1536 blocks)
    k_attn<K0C,0,2,1><<<N0C/4,256,0,stream>>>(qwb0, acat0, 840, times0, ntimes0, nfeats0,
                                              nbr_mask0, nbr_local0, zb1,
                                              time_w, time_b);
    // GEMM2 hop0: BM=64, split-K=4 (768 blocks) + reduce -> f32 z0
    k_gmm<64,4,true,true><<<dim3(2, N0C/64, 4),256,0,stream>>>(acat0,840, Bcat0,D, cb0, part,D, 840, D, N0C);
    k_kred<4,true,true><<<(N0C*D+255)/256,256,0,stream>>>(part, N0C, D, cb0, z0);

    // link prediction
    k_linkpred<<<BSZ,128,0,stream>>>(z0, src,dst,neg, lpWs,lpbs,lpWd,lpbd, lpWo,lpbo, outp);
}